// Round 13
// baseline (334.279 us; speedup 1.0000x reference)
//
#include <hip/hip_runtime.h>
#include <hip/hip_bf16.h>

// Mamba block: B=4, L=2048, D_MODEL=1024, D_INNER=2048, D_STATE=16, DT_RANK=64
#define B_ 4
#define L_ 2048
#define DM 1024
#define DI 2048
#define DSTATE 16
#define DTR 64
#define LC 64            // scan chunk length
#define NC (L_ / LC)     // 32 chunks
#define LOG2E 1.44269504f

typedef unsigned short ushort_t;
typedef __bf16 bf16x8 __attribute__((ext_vector_type(8)));
typedef float f32x4 __attribute__((ext_vector_type(4)));
typedef float f32x16 __attribute__((ext_vector_type(16)));
typedef unsigned short u16x8 __attribute__((ext_vector_type(8)));
typedef unsigned short u16x4 __attribute__((ext_vector_type(4)));

__device__ __forceinline__ ushort_t f2bf(float f) {
    unsigned u = __builtin_bit_cast(unsigned, f);
    unsigned r = (u + 0x7FFFu + ((u >> 16) & 1u)) >> 16;
    return (ushort_t)r;
}
__device__ __forceinline__ float bf2f(ushort_t h) {
    unsigned u = ((unsigned)h) << 16;
    return __builtin_bit_cast(float, u);
}

// ---------------- fused f32 -> bf16 convert for all 5 buffers ----------------
#define CV_E0 1048576
#define CV_E1 (CV_E0 + 49152)
#define CV_E2 (CV_E1 + 32768)
#define CV_E3 (CV_E2 + 524288)
#define CV_E4 (CV_E3 + 2097152)     // total 3751936 quads = 14656 * 256
__global__ __launch_bounds__(256) void k_cvt5(
    const float* __restrict__ s0, ushort_t* __restrict__ d0,
    const float* __restrict__ s1, ushort_t* __restrict__ d1,
    const float* __restrict__ s2, ushort_t* __restrict__ d2,
    const float* __restrict__ s3, ushort_t* __restrict__ d3,
    const float* __restrict__ s4, ushort_t* __restrict__ d4) {
    int g = blockIdx.x * 256 + threadIdx.x;
    const float* s;
    ushort_t* dst;
    int i;
    if (g < CV_E0)      { s = s0; dst = d0; i = g * 4; }
    else if (g < CV_E1) { s = s1; dst = d1; i = (g - CV_E0) * 4; }
    else if (g < CV_E2) { s = s2; dst = d2; i = (g - CV_E1) * 4; }
    else if (g < CV_E3) { s = s3; dst = d3; i = (g - CV_E2) * 4; }
    else                { s = s4; dst = d4; i = (g - CV_E3) * 4; }
    float4 v = *reinterpret_cast<const float4*>(s + i);
    ushort4 o;
    o.x = f2bf(v.x); o.y = f2bf(v.y); o.z = f2bf(v.z); o.w = f2bf(v.w);
    *reinterpret_cast<ushort4*>(dst + i) = o;
}

// ============ pipelined MFMA GEMM machinery ============
#define FENCE asm volatile("" ::: "memory")
#define VM4 asm volatile("s_waitcnt vmcnt(4)" ::: "memory")
#define VM3 asm volatile("s_waitcnt vmcnt(3)" ::: "memory")
#define VM0 asm volatile("s_waitcnt vmcnt(0)" ::: "memory")

// -------- 256x128 BK=32 merged-phase GEMM, 3-buffer ring (72 KB LDS) --------
// 512 threads, 8 waves. 2 blocks/CU. Known-good (round 12).
template <int KK, int LDC, int NT>
__global__ __launch_bounds__(512, 2) void k_gemmP(const ushort_t* __restrict__ Aq,
                                                  const ushort_t* __restrict__ Bq,
                                                  ushort_t* __restrict__ C) {
    __shared__ ushort_t lds[36864];  // 72 KB: 3 buffers x (A 8192 + B 4096 elems)
    const int tid = threadIdx.x;
    const int w = tid >> 6, lane = tid & 63;
    const int l15 = lane & 15;
    const int wm = w >> 2, wn = w & 3;
    const int bid = blockIdx.x;
    const int tm = bid & 31, tn = bid >> 5;
    const int row0 = tm * 256, col0 = tn * 128;

    const int rs = w * 16 + (lane >> 2);
    const int lcs = (lane & 3) ^ ((lane >> 3) & 3);
    const int pcr = ((lane >> 4) ^ ((l15 >> 1) & 3)) * 8;
    const int aoff = wm * 4096 + l15 * 32 + pcr;
    const int boff = 8192 + wn * 1024 + l15 * 32 + pcr;

    auto stg = [&](int buf, int t) {
        const ushort_t* sa = Aq + (size_t)(row0 + rs) * KK + t * 32 + lcs * 8;
        __builtin_amdgcn_global_load_lds(
            (const __attribute__((address_space(1))) void*)sa,
            (__attribute__((address_space(3))) void*)&lds[buf * 12288 + w * 512], 16, 0, 0);
        __builtin_amdgcn_global_load_lds(
            (const __attribute__((address_space(1))) void*)(sa + (size_t)128 * KK),
            (__attribute__((address_space(3))) void*)&lds[buf * 12288 + 4096 + w * 512], 16, 0, 0);
        const ushort_t* sb = Bq + (size_t)(col0 + rs) * KK + t * 32 + lcs * 8;
        __builtin_amdgcn_global_load_lds(
            (const __attribute__((address_space(1))) void*)sb,
            (__attribute__((address_space(3))) void*)&lds[buf * 12288 + 8192 + w * 512], 16, 0, 0);
    };

    f32x4 acc[8][2] = {};

#define GPHASE(BUF, STAGE_STMT, WAIT_STMT)                                        \
    {                                                                             \
        bf16x8 av[8], bv[2];                                                      \
        _Pragma("unroll") for (int i_ = 0; i_ < 8; ++i_)                          \
            av[i_] = *(const bf16x8*)&lds[(BUF) * 12288 + aoff + i_ * 512];       \
        _Pragma("unroll") for (int i_ = 0; i_ < 2; ++i_)                          \
            bv[i_] = *(const bf16x8*)&lds[(BUF) * 12288 + boff + i_ * 512];       \
        STAGE_STMT;                                                               \
        FENCE; __builtin_amdgcn_s_barrier(); FENCE;                               \
        asm volatile("s_waitcnt lgkmcnt(0)" ::: "memory");                        \
        __builtin_amdgcn_sched_barrier(0);                                        \
        __builtin_amdgcn_s_setprio(1);                                            \
        _Pragma("unroll") for (int i_ = 0; i_ < 8; ++i_)                          \
            _Pragma("unroll") for (int j_ = 0; j_ < 2; ++j_)                      \
                acc[i_][j_] = __builtin_amdgcn_mfma_f32_16x16x32_bf16(            \
                    av[i_], bv[j_], acc[i_][j_], 0, 0, 0);                        \
        __builtin_amdgcn_s_setprio(0);                                            \
        WAIT_STMT;                                                                \
        FENCE; __builtin_amdgcn_s_barrier(); FENCE;                               \
    }

    stg(0, 0); stg(1, 1);   // 6 loads in flight
    VM3;                     // tile 0's 3 landed
    FENCE; __builtin_amdgcn_s_barrier(); FENCE;

#pragma unroll 1
    for (int k = 0; k < (NT - 2) / 3; ++k) {
        const int t0 = 3 * k;
        GPHASE(0, stg(2, t0 + 2), VM3);
        GPHASE(1, stg(0, t0 + 3), VM3);
        GPHASE(2, stg(1, t0 + 4), VM3);
    }
    if constexpr ((NT - 2) % 3 == 2) {
        GPHASE(0, stg(2, NT - 2), VM3);
        GPHASE(1, stg(0, NT - 1), VM3);
        GPHASE(2, (void)0, VM0);
        GPHASE(0, (void)0, (void)0);
    } else {
        GPHASE(0, (void)0, VM0);
        GPHASE(1, (void)0, (void)0);
    }
#undef GPHASE

#pragma unroll
    for (int mf = 0; mf < 8; ++mf)
#pragma unroll
        for (int nf = 0; nf < 2; ++nf) {
            int col = col0 + wn * 32 + nf * 16 + l15;
#pragma unroll
            for (int r = 0; r < 4; ++r) {
                int row = row0 + wm * 128 + mf * 16 + (lane >> 4) * 4 + r;
                C[(size_t)row * LDC + col] = f2bf(acc[mf][nf][r]);
            }
        }
}

// -------- 128x128 BK=32 merged-phase GEMM, 3-buffer ring (48 KB LDS) --------
// 256 threads, 4 waves (wm2 x wn2, 64x64 per wave). 3 blocks/CU. Grid must be
// tilesM x tilesN blocks. 4 loads/tile -> VM4 ladder. Used for out_proj.
template <int KK, int LDC, int NT, int TM>
__global__ __launch_bounds__(256, 3) void k_gemmQ(const ushort_t* __restrict__ Aq,
                                                  const ushort_t* __restrict__ Bq,
                                                  ushort_t* __restrict__ C) {
    __shared__ ushort_t lds[24576];  // 48 KB: 3 buffers x (A 4096 + B 4096 elems)
    const int tid = threadIdx.x;
    const int w = tid >> 6, lane = tid & 63;
    const int l15 = lane & 15;
    const int wm = w >> 1, wn = w & 1;
    const int bid = blockIdx.x;
    const int tm = bid & (TM - 1), tn = bid / TM;  // TM consecutive bids share B
    const int row0 = tm * 128, col0 = tn * 128;

    const int rs = w * 16 + (lane >> 2);           // row within 64-row group
    const int lcs = (lane & 3) ^ ((lane >> 3) & 3);
    const int pcr = ((lane >> 4) ^ ((l15 >> 1) & 3)) * 8;
    const int aoff = wm * 2048 + l15 * 32 + pcr;
    const int boff = 4096 + wn * 2048 + l15 * 32 + pcr;

    auto stg = [&](int buf, int t) {
        const ushort_t* sa = Aq + (size_t)(row0 + rs) * KK + t * 32 + lcs * 8;
        __builtin_amdgcn_global_load_lds(
            (const __attribute__((address_space(1))) void*)sa,
            (__attribute__((address_space(3))) void*)&lds[buf * 8192 + w * 512], 16, 0, 0);
        __builtin_amdgcn_global_load_lds(
            (const __attribute__((address_space(1))) void*)(sa + (size_t)64 * KK),
            (__attribute__((address_space(3))) void*)&lds[buf * 8192 + 2048 + w * 512], 16, 0, 0);
        const ushort_t* sb = Bq + (size_t)(col0 + rs) * KK + t * 32 + lcs * 8;
        __builtin_amdgcn_global_load_lds(
            (const __attribute__((address_space(1))) void*)sb,
            (__attribute__((address_space(3))) void*)&lds[buf * 8192 + 4096 + w * 512], 16, 0, 0);
        __builtin_amdgcn_global_load_lds(
            (const __attribute__((address_space(1))) void*)(sb + (size_t)64 * KK),
            (__attribute__((address_space(3))) void*)&lds[buf * 8192 + 6144 + w * 512], 16, 0, 0);
    };

    f32x4 acc[4][4] = {};

#define QPHASE(BUF, STAGE_STMT, WAIT_STMT)                                        \
    {                                                                             \
        bf16x8 av[4], bv[4];                                                      \
        _Pragma("unroll") for (int i_ = 0; i_ < 4; ++i_)                          \
            av[i_] = *(const bf16x8*)&lds[(BUF) * 8192 + aoff + i_ * 512];        \
        _Pragma("unroll") for (int i_ = 0; i_ < 4; ++i_)                          \
            bv[i_] = *(const bf16x8*)&lds[(BUF) * 8192 + boff + i_ * 512];        \
        STAGE_STMT;                                                               \
        FENCE; __builtin_amdgcn_s_barrier(); FENCE;                               \
        asm volatile("s_waitcnt lgkmcnt(0)" ::: "memory");                        \
        __builtin_amdgcn_sched_barrier(0);                                        \
        __builtin_amdgcn_s_setprio(1);                                            \
        _Pragma("unroll") for (int i_ = 0; i_ < 4; ++i_)                          \
            _Pragma("unroll") for (int j_ = 0; j_ < 4; ++j_)                      \
                acc[i_][j_] = __builtin_amdgcn_mfma_f32_16x16x32_bf16(            \
                    av[i_], bv[j_], acc[i_][j_], 0, 0, 0);                        \
        __builtin_amdgcn_s_setprio(0);                                            \
        WAIT_STMT;                                                                \
        FENCE; __builtin_amdgcn_s_barrier(); FENCE;                               \
    }

    stg(0, 0); stg(1, 1);   // 8 loads in flight
    VM4;                     // tile 0's 4 landed
    FENCE; __builtin_amdgcn_s_barrier(); FENCE;

#pragma unroll 1
    for (int k = 0; k < (NT - 2) / 3; ++k) {
        const int t0 = 3 * k;
        QPHASE(0, stg(2, t0 + 2), VM4);
        QPHASE(1, stg(0, t0 + 3), VM4);
        QPHASE(2, stg(1, t0 + 4), VM4);
    }
    if constexpr ((NT - 2) % 3 == 2) {
        QPHASE(0, stg(2, NT - 2), VM4);
        QPHASE(1, stg(0, NT - 1), VM4);
        QPHASE(2, (void)0, VM0);
        QPHASE(0, (void)0, (void)0);
    } else {
        QPHASE(0, (void)0, VM0);
        QPHASE(1, (void)0, (void)0);
    }
#undef QPHASE

#pragma unroll
    for (int mf = 0; mf < 4; ++mf)
#pragma unroll
        for (int nf = 0; nf < 4; ++nf) {
            int col = col0 + wn * 64 + nf * 16 + l15;
#pragma unroll
            for (int r = 0; r < 4; ++r) {
                int row = row0 + wm * 64 + mf * 16 + (lane >> 4) * 4 + r;
                C[(size_t)row * LDC + col] = f2bf(acc[mf][nf][r]);
            }
        }
}

// ---------------- m97-structure bf16 MFMA GEMM (x_proj / dt_proj) ------------
template <int EPI, bool OUTBF>
__global__ __launch_bounds__(256) void k_gemm2(
    const ushort_t* __restrict__ A, const ushort_t* __restrict__ Bw,
    void* __restrict__ C, const float* __restrict__ bias,
    int M, int N, int K, int lda, int ldb, int ldc, int tilesM) {
    __shared__ ushort_t As[128 * 64];
    __shared__ ushort_t Bs[128 * 64];
    int tid = threadIdx.x;
    int lane = tid & 63, wv = tid >> 6;
    int wr = wv >> 1, wc = wv & 1;
    int bid = blockIdx.x;
    int tilesN = gridDim.x / tilesM;
    int per = 8 * tilesN;
    int grp = bid / per, within = bid % per;
    int tm = grp * 8 + (within & 7);
    int tn = within >> 3;
    int row0 = tm * 128, col0 = tn * 128;
    int kchunk = K / gridDim.z;
    int kbeg = blockIdx.z * kchunk, kend = kbeg + kchunk;
    float* Cf = (float*)C + (size_t)blockIdx.z * (size_t)M * ldc;

    int sr = lane >> 3;
    int sj = lane & 7;
    f32x4 acc[4][4] = {};

    for (int k0 = kbeg; k0 < kend; k0 += 64) {
        __syncthreads();
#pragma unroll
        for (int i = 0; i < 4; ++i) {
            int slot = wv * 4 + i;
            int r = slot * 8 + sr;
            int jA = sj ^ (r & 7);
            __builtin_amdgcn_global_load_lds(
                (const __attribute__((address_space(1))) void*)&A[(size_t)(row0 + r) * lda + k0 + jA * 8],
                (__attribute__((address_space(3))) void*)&As[slot * 512], 16, 0, 0);
            __builtin_amdgcn_global_load_lds(
                (const __attribute__((address_space(1))) void*)&Bw[(size_t)(col0 + r) * ldb + k0 + jA * 8],
                (__attribute__((address_space(3))) void*)&Bs[slot * 512], 16, 0, 0);
        }
        __syncthreads();
#pragma unroll
        for (int kk = 0; kk < 2; ++kk) {
            int co = kk * 32 + (lane >> 4) * 8;
            int sx = (lane & 7) << 3;
            bf16x8 af[4], bfr[4];
#pragma unroll
            for (int m = 0; m < 4; ++m) {
                int rw = wr * 64 + m * 16 + (lane & 15);
                af[m] = *reinterpret_cast<const bf16x8*>(&As[rw * 64 + (co ^ sx)]);
            }
#pragma unroll
            for (int n = 0; n < 4; ++n) {
                int rw = wc * 64 + n * 16 + (lane & 15);
                bfr[n] = *reinterpret_cast<const bf16x8*>(&Bs[rw * 64 + (co ^ sx)]);
            }
#pragma unroll
            for (int m = 0; m < 4; ++m)
#pragma unroll
                for (int n = 0; n < 4; ++n)
                    acc[m][n] = __builtin_amdgcn_mfma_f32_16x16x32_bf16(af[m], bfr[n], acc[m][n], 0, 0, 0);
        }
    }

#pragma unroll
    for (int m = 0; m < 4; ++m) {
#pragma unroll
        for (int n = 0; n < 4; ++n) {
            int col = col0 + wc * 64 + n * 16 + (lane & 15);
            if (col >= N) continue;
#pragma unroll
            for (int r = 0; r < 4; ++r) {
                int row = row0 + wr * 64 + m * 16 + (lane >> 4) * 4 + r;
                float v = acc[m][n][r];
                if (EPI == 1) {
                    v += bias[col];
                    v = (v > 20.f) ? v : log1pf(__expf(v));
                }
                if (OUTBF)
                    ((ushort_t*)C)[(size_t)row * ldc + col] = f2bf(v);
                else
                    Cf[(size_t)row * ldc + col] = v;
            }
        }
    }
}

// ---------------- split-K partial reduce (4 partials f32 -> bf16) ------------
__global__ __launch_bounds__(256) void k_red4(const float* __restrict__ p,
                                              ushort_t* __restrict__ o,
                                              int n, int stride) {
    int i = (blockIdx.x * 256 + threadIdx.x) * 4;
    if (i >= n) return;
    f32x4 a = *reinterpret_cast<const f32x4*>(&p[i]);
    f32x4 b = *reinterpret_cast<const f32x4*>(&p[i + stride]);
    f32x4 c = *reinterpret_cast<const f32x4*>(&p[i + 2 * stride]);
    f32x4 d = *reinterpret_cast<const f32x4*>(&p[i + 3 * stride]);
    ushort4 r;
    r.x = f2bf(a[0] + b[0] + c[0] + d[0]);
    r.y = f2bf(a[1] + b[1] + c[1] + d[1]);
    r.z = f2bf(a[2] + b[2] + c[2] + d[2]);
    r.w = f2bf(a[3] + b[3] + c[3] + d[3]);
    *reinterpret_cast<ushort4*>(&o[i]) = r;
}

// ---------------- depthwise causal conv (width 4) + SiLU ----------------
__global__ __launch_bounds__(256) void k_conv(const ushort_t* __restrict__ xz,
                                              const float* __restrict__ w,
                                              const float* __restrict__ bias,
                                              ushort_t* __restrict__ out) {
    int d = blockIdx.x * 256 + threadIdx.x;
    int b = blockIdx.z;
    int t0 = blockIdx.y * 128;
    float w0 = w[d * 4 + 0], w1 = w[d * 4 + 1], w2 = w[d * 4 + 2], w3 = w[d * 4 + 3];
    float bi = bias[d];
    size_t base = ((size_t)b * L_) * (2 * DI) + d;
    size_t obase = ((size_t)b * L_) * DI + d;
    float x0 = (t0 >= 3) ? bf2f(xz[base + (size_t)(t0 - 3) * (2 * DI)]) : 0.f;
    float x1 = (t0 >= 2) ? bf2f(xz[base + (size_t)(t0 - 2) * (2 * DI)]) : 0.f;
    float x2 = (t0 >= 1) ? bf2f(xz[base + (size_t)(t0 - 1) * (2 * DI)]) : 0.f;
    for (int t = t0; t < t0 + 128; ++t) {
        float cur = bf2f(xz[base + (size_t)t * (2 * DI)]);
        float v = w0 * x0 + w1 * x1 + w2 * x2 + w3 * cur + bi;
        v = v / (1.f + __expf(-v));
        out[obase + (size_t)t * DI] = f2bf(v);
        x0 = x1; x1 = x2; x2 = cur;
    }
}

// ---------------- chunked selective scan ----------------
// Phase 1: per-chunk local scan (h=0) -> chunk-final h and sum(dt)
__global__ __launch_bounds__(256) void k_scan1(
    const ushort_t* __restrict__ dt, const ushort_t* __restrict__ xm,
    const ushort_t* __restrict__ dbc, const float* __restrict__ A_log,
    float* __restrict__ hfin, float* __restrict__ dtsum) {
    __shared__ float Bsh[LC][DSTATE];
    int tid = threadIdx.x;
    int d = blockIdx.x * 256 + tid;
    int c = blockIdx.y, b = blockIdx.z;
    f32x16 arow;
    float a1 = __expf(A_log[d * DSTATE]);
    bool ok = true;
#pragma unroll
    for (int s = 0; s < DSTATE; ++s) {
        float av = __expf(A_log[d * DSTATE + s]);
        arow[s] = -av * LOG2E;
        ok = ok && (fabsf(av - (float)(s + 1) * a1) <= 1e-4f * (float)(s + 1) * fabsf(a1) + 1e-6f);
    }
    float arow0 = -a1 * LOG2E;
    size_t rbase = (size_t)b * L_ + (size_t)c * LC;
    {
        int i = tid * 4;
        int t = i >> 4, s0 = i & 15;
        u16x4 v = *reinterpret_cast<const u16x4*>(&dbc[(rbase + t) * 96 + DTR + s0]);
#pragma unroll
        for (int j = 0; j < 4; ++j) Bsh[t][s0 + j] = bf2f(v[j]);
    }
    __syncthreads();
    f32x4 h0 = {}, h1 = {}, h2 = {}, h3 = {};
    float sd = 0.f;
    if (ok) {
        for (int t = 0; t < LC; ++t) {
            size_t ro = rbase + t;
            float dtv = bf2f(dt[ro * DI + d]);
            float xv = bf2f(xm[ro * DI + d]);
            float dx = dtv * xv;
            sd += dtv;
            float p = __builtin_amdgcn_exp2f(dtv * arow0);
            float p2 = p * p, p3 = p2 * p, p4 = p2 * p2;
            f32x4 ea = {p, p2, p3, p4};
            f32x4 eb = ea * p4, ec = eb * p4, ed = ec * p4;
            const f32x4* Bq = reinterpret_cast<const f32x4*>(&Bsh[t][0]);
            h0 = h0 * ea + Bq[0] * dx;
            h1 = h1 * eb + Bq[1] * dx;
            h2 = h2 * ec + Bq[2] * dx;
            h3 = h3 * ed + Bq[3] * dx;
        }
    } else {
        for (int t = 0; t < LC; ++t) {
            size_t ro = rbase + t;
            float dtv = bf2f(dt[ro * DI + d]);
            float xv = bf2f(xm[ro * DI + d]);
            float dx = dtv * xv;
            sd += dtv;
            const f32x4* Bq = reinterpret_cast<const f32x4*>(&Bsh[t][0]);
            f32x4 e0, e1, e2, e3;
#pragma unroll
            for (int j = 0; j < 4; ++j) {
                e0[j] = __builtin_amdgcn_exp2f(dtv * arow[j]);
                e1[j] = __builtin_amdgcn_exp2f(dtv * arow[4 + j]);
                e2[j] = __builtin_amdgcn_exp2f(dtv * arow[8 + j]);
                e3[j] = __builtin_amdgcn_exp2f(dtv * arow[12 + j]);
            }
            h0 = h0 * e0 + Bq[0] * dx;
            h1 = h1 * e1 + Bq[1] * dx;
            h2 = h2 * e2 + Bq[2] * dx;
            h3 = h3 * e3 + Bq[3] * dx;
        }
    }
    size_t hbase = (((size_t)b * NC + c) * DI + d) * DSTATE;
    *reinterpret_cast<f32x4*>(&hfin[hbase + 0]) = h0;
    *reinterpret_cast<f32x4*>(&hfin[hbase + 4]) = h1;
    *reinterpret_cast<f32x4*>(&hfin[hbase + 8]) = h2;
    *reinterpret_cast<f32x4*>(&hfin[hbase + 12]) = h3;
    dtsum[((size_t)b * NC + c) * DI + d] = sd;
}

// Phase 2: sequential carry over chunks; hfin becomes carry-IN per chunk.
__global__ __launch_bounds__(256) void k_scan2(
    float* __restrict__ hfin, const float* __restrict__ dtsum,
    const float* __restrict__ A_log) {
    int gid = blockIdx.x * 256 + threadIdx.x;  // s fastest, then d, then b
    int s = gid & (DSTATE - 1);
    int d = (gid >> 4) & (DI - 1);
    int b = gid >> 15;
    float Av = -__expf(A_log[d * DSTATE + s]) * LOG2E;
    float carry = 0.f;
    for (int c = 0; c < NC; ++c) {
        size_t idx = (((size_t)b * NC + c) * DI + d) * DSTATE + s;
        float loc = hfin[idx];
        hfin[idx] = carry;
        float sd = dtsum[((size_t)b * NC + c) * DI + d];
        carry = __builtin_amdgcn_exp2f(Av * sd) * carry + loc;
    }
}

// Phase 3: local scan with carry-in + D*x + z-gating -> yg (bf16)
__global__ __launch_bounds__(256) void k_scan3(
    const ushort_t* __restrict__ dt, const ushort_t* __restrict__ xm,
    const ushort_t* __restrict__ xz, const ushort_t* __restrict__ dbc,
    const float* __restrict__ A_log, const float* __restrict__ Dp,
    const float* __restrict__ hinit, ushort_t* __restrict__ yg) {
    __shared__ float Bsh[LC][DSTATE];
    __shared__ float Csh[LC][DSTATE];
    int tid = threadIdx.x;
    int d = blockIdx.x * 256 + tid;
    int c = blockIdx.y, b = blockIdx.z;
    f32x16 arow;
    float a1 = __expf(A_log[d * DSTATE]);
    bool ok = true;
#pragma unroll
    for (int s = 0; s < DSTATE; ++s) {
        float av = __expf(A_log[d * DSTATE + s]);
        arow[s] = -av * LOG2E;
        ok = ok && (fabsf(av - (float)(s + 1) * a1) <= 1e-4f * (float)(s + 1) * fabsf(a1) + 1e-6f);
    }
    float arow0 = -a1 * LOG2E;
    float Dd = Dp[d];
    size_t rbase = (size_t)b * L_ + (size_t)c * LC;
    {
        int e0 = tid * 8;
        int t = e0 >> 5, s0 = e0 & 31;
        u16x8 v = *reinterpret_cast<const u16x8*>(&dbc[(rbase + t) * 96 + DTR + s0]);
#pragma unroll
        for (int j = 0; j < 8; ++j) {
            int s = s0 + j;
            float f = bf2f(v[j]);
            if (s < DSTATE) Bsh[t][s] = f;
            else Csh[t][s - DSTATE] = f;
        }
    }
    __syncthreads();
    size_t hbase = (((size_t)b * NC + c) * DI + d) * DSTATE;
    f32x4 h0 = *reinterpret_cast<const f32x4*>(&hinit[hbase + 0]);
    f32x4 h1 = *reinterpret_cast<const f32x4*>(&hinit[hbase + 4]);
    f32x4 h2 = *reinterpret_cast<const f32x4*>(&hinit[hbase + 8]);
    f32x4 h3 = *reinterpret_cast<const f32x4*>(&hinit[hbase + 12]);
    if (ok) {
        for (int t = 0; t < LC; ++t) {
            size_t ro = rbase + t;
            float dtv = bf2f(dt[ro * DI + d]);
            float xv = bf2f(xm[ro * DI + d]);
            float zv = bf2f(xz[ro * (2 * DI) + DI + d]);
            float dx = dtv * xv;
            float p = __builtin_amdgcn_exp2f(dtv * arow0);
            float p2 = p * p, p3 = p2 * p, p4 = p2 * p2;
            f32x4 ea = {p, p2, p3, p4};
            f32x4 eb = ea * p4, ec = eb * p4, ed = ec * p4;
            const f32x4* Bq = reinterpret_cast<const f32x4*>(&Bsh[t][0]);
            const f32x4* Cq = reinterpret_cast<const f32x4*>(&Csh[t][0]);
            h0 = h0 * ea + Bq[0] * dx;
            h1 = h1 * eb + Bq[1] * dx;
            h2 = h2 * ec + Bq[2] * dx;
            h3 = h3 * ed + Bq[3] * dx;
            f32x4 y4 = h0 * Cq[0] + h1 * Cq[1] + h2 * Cq[2] + h3 * Cq[3];
            float y = (y4[0] + y4[1]) + (y4[2] + y4[3]) + Dd * xv;
            y *= zv / (1.f + __expf(-zv));
            yg[ro * DI + d] = f2bf(y);
        }
    } else {
        for (int t = 0; t < LC; ++t) {
            size_t ro = rbase + t;
            float dtv = bf2f(dt[ro * DI + d]);
            float xv = bf2f(xm[ro * DI + d]);
            float zv = bf2f(xz[ro * (2 * DI) + DI + d]);
            float dx = dtv * xv;
            const f32x4* Bq = reinterpret_cast<const f32x4*>(&Bsh[t][0]);
            const f32x4* Cq = reinterpret_cast<const f32x4*>(&Csh[t][0]);
            f32x4 e0, e1, e2, e3;
#pragma unroll
            for (int j = 0; j < 4; ++j) {
                e0[j] = __builtin_amdgcn_exp2f(dtv * arow[j]);
                e1[j] = __builtin_amdgcn_exp2f(dtv * arow[4 + j]);
                e2[j] = __builtin_amdgcn_exp2f(dtv * arow[8 + j]);
                e3[j] = __builtin_amdgcn_exp2f(dtv * arow[12 + j]);
            }
            h0 = h0 * e0 + Bq[0] * dx;
            h1 = h1 * e1 + Bq[1] * dx;
            h2 = h2 * e2 + Bq[2] * dx;
            h3 = h3 * e3 + Bq[3] * dx;
            f32x4 y4 = h0 * Cq[0] + h1 * Cq[1] + h2 * Cq[2] + h3 * Cq[3];
            float y = (y4[0] + y4[1]) + (y4[2] + y4[3]) + Dd * xv;
            y *= zv / (1.f + __expf(-zv));
            yg[ro * DI + d] = f2bf(y);
        }
    }
}

// ---------------- residual + LayerNorm (bf16 mamba-out) ----------------
__global__ __launch_bounds__(256) void k_ln(const ushort_t* __restrict__ mo,
                                            const float* __restrict__ x,
                                            const float* __restrict__ g,
                                            const float* __restrict__ be,
                                            float* __restrict__ out) {
    __shared__ float red[8];
    size_t r = blockIdx.x;
    int tid = threadIdx.x;
    ushort4 mv = *reinterpret_cast<const ushort4*>(&mo[r * DM + tid * 4]);
    float4 xv = *reinterpret_cast<const float4*>(&x[r * DM + tid * 4]);
    float h0 = bf2f(mv.x) + xv.x, h1 = bf2f(mv.y) + xv.y;
    float h2 = bf2f(mv.z) + xv.z, h3 = bf2f(mv.w) + xv.w;
    float s = h0 + h1 + h2 + h3;
    float q = h0 * h0 + h1 * h1 + h2 * h2 + h3 * h3;
#pragma unroll
    for (int o = 32; o > 0; o >>= 1) {
        s += __shfl_down(s, o);
        q += __shfl_down(q, o);
    }
    int lane = tid & 63, wid = tid >> 6;
    if (lane == 0) { red[wid] = s; red[4 + wid] = q; }
    __syncthreads();
    s = red[0] + red[1] + red[2] + red[3];
    q = red[4] + red[5] + red[6] + red[7];
    float mu = s * (1.f / DM);
    float var = q * (1.f / DM) - mu * mu;
    float rs = rsqrtf(var + 1e-5f);
    float4 gv = *reinterpret_cast<const float4*>(&g[tid * 4]);
    float4 bv = *reinterpret_cast<const float4*>(&be[tid * 4]);
    float4 o;
    o.x = (h0 - mu) * rs * gv.x + bv.x;
    o.y = (h1 - mu) * rs * gv.y + bv.y;
    o.z = (h2 - mu) * rs * gv.z + bv.z;
    o.w = (h3 - mu) * rs * gv.w + bv.w;
    *reinterpret_cast<float4*>(&out[r * DM + tid * 4]) = o;
}

extern "C" void kernel_launch(void* const* d_in, const int* in_sizes, int n_in,
                              void* d_out, int out_size, void* d_ws, size_t ws_size,
                              hipStream_t stream) {
    const float* x      = (const float*)d_in[0];   // (B,L,DM)
    const float* w_in   = (const float*)d_in[1];   // (2*DI, DM)
    const float* conv_w = (const float*)d_in[2];   // (DI,1,4)
    const float* conv_b = (const float*)d_in[3];   // (DI)
    const float* w_xp   = (const float*)d_in[4];   // (96, DI)
    const float* w_dt   = (const float*)d_in[5];   // (DI, 64)
    const float* dt_b   = (const float*)d_in[6];   // (DI)
    const float* A_log  = (const float*)d_in[7];   // (DI,16)
    const float* Dp     = (const float*)d_in[8];   // (DI)
    const float* w_out  = (const float*)d_in[9];   // (DM, DI)
    const float* ln_g   = (const float*)d_in[10];
    const float* ln_b   = (const float*)d_in[11];
    float* out = (float*)d_out;

    char* ws = (char*)d_ws;
    size_t off = 0;
    auto alloc = [&](size_t bytes) -> void* {
        void* p = ws + off;
        off += (bytes + 255) & ~(size_t)255;
        return p;
    };
    const int M = B_ * L_;  // 8192
    ushort_t* w_in_b  = (ushort_t*)alloc((size_t)2 * DI * DM * 2);
    ushort_t* w_xp_b  = (ushort_t*)alloc((size_t)96 * DI * 2);
    ushort_t* w_dt_b  = (ushort_t*)alloc((size_t)DI * DTR * 2);
    ushort_t* w_out_b = (ushort_t*)alloc((size_t)DM * DI * 2);
    ushort_t* x_b     = (ushort_t*)alloc((size_t)M * DM * 2);   // 16.8 MB
    ushort_t* xz      = (ushort_t*)alloc((size_t)M * 2 * DI * 2);
    ushort_t* xm      = (ushort_t*)alloc((size_t)M * DI * 2);
    ushort_t* dbc     = (ushort_t*)alloc((size_t)M * 96 * 2);
    ushort_t* dtb     = (ushort_t*)alloc((size_t)M * DI * 2);   // bf16 dt (33.5 MB)
    ushort_t* yg      = (ushort_t*)alloc((size_t)M * DI * 2);
    float*    dtsum   = (float*)alloc((size_t)B_ * NC * DI * 4);
    float*    dbc_p   = (float*)alloc((size_t)4 * M * 96 * 4);  // split-K partials
    ushort_t* mo      = dtb;           // alias: dt dead after scan3 (bf16 mo fits)
    float*    hfin    = (float*)x_b;   // alias: x_b dead after in_proj

    // fused f32->bf16 conversion of all inputs (1 launch)
    k_cvt5<<<dim3(CV_E4 / 256), 256, 0, stream>>>(
        w_in, w_in_b, w_xp, w_xp_b, w_dt, w_dt_b, w_out, w_out_b, x, x_b);

    // in_proj: xz[8192,4096] = x_b @ w_in_b^T  -- two N-half launches (512 blk)
    k_gemmP<1024, 4096, 32><<<dim3(512), 512, 0, stream>>>(x_b, w_in_b, xz);
    k_gemmP<1024, 4096, 32><<<dim3(512), 512, 0, stream>>>(
        x_b, w_in_b + (size_t)2048 * 1024, xz + 2048);
    // conv + silu
    k_conv<<<dim3(DI / 256, L_ / 128, B_), 256, 0, stream>>>(xz, conv_w, conv_b, xm);
    // x_proj (split-K=4): dbc_p[z][M,96] = xm @ w_xp[96,2048]^T (K chunk 512)
    k_gemm2<0, false><<<dim3(64, 1, 4), 256, 0, stream>>>(
        xm, w_xp_b, dbc_p, nullptr, M, 96, DI, DI, DI, 96, 64);
    k_red4<<<dim3((M * 96 / 4 + 255) / 256), 256, 0, stream>>>(dbc_p, dbc, M * 96, M * 96);
    // dt_proj + softplus -> bf16
    k_gemm2<1, true><<<dim3(64 * 16, 1, 1), 256, 0, stream>>>(
        dbc, w_dt_b, dtb, dt_b, M, DI, DTR, 96, DTR, DI, 64);
    // chunked selective scan
    k_scan1<<<dim3(DI / 256, NC, B_), 256, 0, stream>>>(dtb, xm, dbc, A_log, hfin, dtsum);
    k_scan2<<<dim3(B_ * DI * DSTATE / 256), 256, 0, stream>>>(hfin, dtsum, A_log);
    k_scan3<<<dim3(DI / 256, NC, B_), 256, 0, stream>>>(dtb, xm, xz, dbc, A_log, Dp, hfin, yg);
    // out_proj: mo[8192,1024](bf16) = yg @ w_out^T  (128^2, 3 blocks/CU, 512 blk)
    k_gemmQ<2048, 1024, 64, 64><<<dim3(512), 256, 0, stream>>>(yg, w_out_b, mo);
    // residual + layernorm
    k_ln<<<dim3(M), 256, 0, stream>>>(mo, x, ln_g, ln_b, out);
}

// Round 14
// 287.122 us; speedup vs baseline: 1.1642x; 1.1642x over previous
//
#include <hip/hip_runtime.h>
#include <hip/hip_bf16.h>

// Mamba block: B=4, L=2048, D_MODEL=1024, D_INNER=2048, D_STATE=16, DT_RANK=64
#define B_ 4
#define L_ 2048
#define DM 1024
#define DI 2048
#define DSTATE 16
#define DTR 64
#define LC 64            // scan chunk length
#define NC (L_ / LC)     // 32 chunks
#define LOG2E 1.44269504f

typedef unsigned short ushort_t;
typedef __bf16 bf16x8 __attribute__((ext_vector_type(8)));
typedef float f32x4 __attribute__((ext_vector_type(4)));
typedef float f32x16 __attribute__((ext_vector_type(16)));
typedef unsigned short u16x8 __attribute__((ext_vector_type(8)));
typedef unsigned short u16x4 __attribute__((ext_vector_type(4)));

__device__ __forceinline__ ushort_t f2bf(float f) {
    unsigned u = __builtin_bit_cast(unsigned, f);
    unsigned r = (u + 0x7FFFu + ((u >> 16) & 1u)) >> 16;
    return (ushort_t)r;
}
__device__ __forceinline__ float bf2f(ushort_t h) {
    unsigned u = ((unsigned)h) << 16;
    return __builtin_bit_cast(float, u);
}

// ---------------- fused f32 -> bf16 convert for all 5 buffers ----------------
#define CV_E0 1048576
#define CV_E1 (CV_E0 + 49152)
#define CV_E2 (CV_E1 + 32768)
#define CV_E3 (CV_E2 + 524288)
#define CV_E4 (CV_E3 + 2097152)     // total 3751936 quads = 14656 * 256
__global__ __launch_bounds__(256) void k_cvt5(
    const float* __restrict__ s0, ushort_t* __restrict__ d0,
    const float* __restrict__ s1, ushort_t* __restrict__ d1,
    const float* __restrict__ s2, ushort_t* __restrict__ d2,
    const float* __restrict__ s3, ushort_t* __restrict__ d3,
    const float* __restrict__ s4, ushort_t* __restrict__ d4) {
    int g = blockIdx.x * 256 + threadIdx.x;
    const float* s;
    ushort_t* dst;
    int i;
    if (g < CV_E0)      { s = s0; dst = d0; i = g * 4; }
    else if (g < CV_E1) { s = s1; dst = d1; i = (g - CV_E0) * 4; }
    else if (g < CV_E2) { s = s2; dst = d2; i = (g - CV_E1) * 4; }
    else if (g < CV_E3) { s = s3; dst = d3; i = (g - CV_E2) * 4; }
    else                { s = s4; dst = d4; i = (g - CV_E3) * 4; }
    float4 v = *reinterpret_cast<const float4*>(s + i);
    ushort4 o;
    o.x = f2bf(v.x); o.y = f2bf(v.y); o.z = f2bf(v.z); o.w = f2bf(v.w);
    *reinterpret_cast<ushort4*>(dst + i) = o;
}

// ============ pipelined MFMA GEMM machinery ============
#define FENCE asm volatile("" ::: "memory")
#define VM3 asm volatile("s_waitcnt vmcnt(3)" ::: "memory")
#define VM0 asm volatile("s_waitcnt vmcnt(0)" ::: "memory")

// -------- 256x128 BK=32 merged-phase GEMM, 3-buffer ring (72 KB LDS) --------
// 512 threads, 8 waves, 2 blocks/CU. Known-good (round 12).
template <int KK, int LDC, int NT>
__global__ __launch_bounds__(512, 2) void k_gemmP(const ushort_t* __restrict__ Aq,
                                                  const ushort_t* __restrict__ Bq,
                                                  ushort_t* __restrict__ C) {
    __shared__ ushort_t lds[36864];  // 72 KB: 3 buffers x (A 8192 + B 4096 elems)
    const int tid = threadIdx.x;
    const int w = tid >> 6, lane = tid & 63;
    const int l15 = lane & 15;
    const int wm = w >> 2, wn = w & 3;
    const int bid = blockIdx.x;
    const int tm = bid & 31, tn = bid >> 5;
    const int row0 = tm * 256, col0 = tn * 128;

    const int rs = w * 16 + (lane >> 2);
    const int lcs = (lane & 3) ^ ((lane >> 3) & 3);
    const int pcr = ((lane >> 4) ^ ((l15 >> 1) & 3)) * 8;
    const int aoff = wm * 4096 + l15 * 32 + pcr;
    const int boff = 8192 + wn * 1024 + l15 * 32 + pcr;

    auto stg = [&](int buf, int t) {
        const ushort_t* sa = Aq + (size_t)(row0 + rs) * KK + t * 32 + lcs * 8;
        __builtin_amdgcn_global_load_lds(
            (const __attribute__((address_space(1))) void*)sa,
            (__attribute__((address_space(3))) void*)&lds[buf * 12288 + w * 512], 16, 0, 0);
        __builtin_amdgcn_global_load_lds(
            (const __attribute__((address_space(1))) void*)(sa + (size_t)128 * KK),
            (__attribute__((address_space(3))) void*)&lds[buf * 12288 + 4096 + w * 512], 16, 0, 0);
        const ushort_t* sb = Bq + (size_t)(col0 + rs) * KK + t * 32 + lcs * 8;
        __builtin_amdgcn_global_load_lds(
            (const __attribute__((address_space(1))) void*)sb,
            (__attribute__((address_space(3))) void*)&lds[buf * 12288 + 8192 + w * 512], 16, 0, 0);
    };

    f32x4 acc[8][2] = {};

#define GPHASE(BUF, STAGE_STMT, WAIT_STMT)                                        \
    {                                                                             \
        bf16x8 av[8], bv[2];                                                      \
        _Pragma("unroll") for (int i_ = 0; i_ < 8; ++i_)                          \
            av[i_] = *(const bf16x8*)&lds[(BUF) * 12288 + aoff + i_ * 512];       \
        _Pragma("unroll") for (int i_ = 0; i_ < 2; ++i_)                          \
            bv[i_] = *(const bf16x8*)&lds[(BUF) * 12288 + boff + i_ * 512];       \
        STAGE_STMT;                                                               \
        FENCE; __builtin_amdgcn_s_barrier(); FENCE;                               \
        asm volatile("s_waitcnt lgkmcnt(0)" ::: "memory");                        \
        __builtin_amdgcn_sched_barrier(0);                                        \
        __builtin_amdgcn_s_setprio(1);                                            \
        _Pragma("unroll") for (int i_ = 0; i_ < 8; ++i_)                          \
            _Pragma("unroll") for (int j_ = 0; j_ < 2; ++j_)                      \
                acc[i_][j_] = __builtin_amdgcn_mfma_f32_16x16x32_bf16(            \
                    av[i_], bv[j_], acc[i_][j_], 0, 0, 0);                        \
        __builtin_amdgcn_s_setprio(0);                                            \
        WAIT_STMT;                                                                \
        FENCE; __builtin_amdgcn_s_barrier(); FENCE;                               \
    }

    stg(0, 0); stg(1, 1);   // 6 loads in flight
    VM3;                     // tile 0's 3 landed
    FENCE; __builtin_amdgcn_s_barrier(); FENCE;

#pragma unroll 1
    for (int k = 0; k < (NT - 2) / 3; ++k) {
        const int t0 = 3 * k;
        GPHASE(0, stg(2, t0 + 2), VM3);
        GPHASE(1, stg(0, t0 + 3), VM3);
        GPHASE(2, stg(1, t0 + 4), VM3);
    }
    if constexpr ((NT - 2) % 3 == 2) {
        GPHASE(0, stg(2, NT - 2), VM3);
        GPHASE(1, stg(0, NT - 1), VM3);
        GPHASE(2, (void)0, VM0);
        GPHASE(0, (void)0, (void)0);
    } else {
        GPHASE(0, (void)0, VM0);
        GPHASE(1, (void)0, (void)0);
    }
#undef GPHASE

#pragma unroll
    for (int mf = 0; mf < 8; ++mf)
#pragma unroll
        for (int nf = 0; nf < 2; ++nf) {
            int col = col0 + wn * 32 + nf * 16 + l15;
#pragma unroll
            for (int r = 0; r < 4; ++r) {
                int row = row0 + wm * 128 + mf * 16 + (lane >> 4) * 4 + r;
                C[(size_t)row * LDC + col] = f2bf(acc[mf][nf][r]);
            }
        }
}

// ---------------- m97-structure bf16 MFMA GEMM (x_proj / dt_proj) ------------
// EPI=1: fast branchless softplus via v_exp_f32 + v_log_f32 (NOT libm log1pf,
// which goes through a slow ocml path -> 70us epilogue, round-13 finding).
template <int EPI, bool OUTBF>
__global__ __launch_bounds__(256) void k_gemm2(
    const ushort_t* __restrict__ A, const ushort_t* __restrict__ Bw,
    void* __restrict__ C, const float* __restrict__ bias,
    int M, int N, int K, int lda, int ldb, int ldc, int tilesM) {
    __shared__ ushort_t As[128 * 64];
    __shared__ ushort_t Bs[128 * 64];
    int tid = threadIdx.x;
    int lane = tid & 63, wv = tid >> 6;
    int wr = wv >> 1, wc = wv & 1;
    int bid = blockIdx.x;
    int tilesN = gridDim.x / tilesM;
    int per = 8 * tilesN;
    int grp = bid / per, within = bid % per;
    int tm = grp * 8 + (within & 7);
    int tn = within >> 3;
    int row0 = tm * 128, col0 = tn * 128;
    int kchunk = K / gridDim.z;
    int kbeg = blockIdx.z * kchunk, kend = kbeg + kchunk;
    float* Cf = (float*)C + (size_t)blockIdx.z * (size_t)M * ldc;

    int sr = lane >> 3;
    int sj = lane & 7;
    f32x4 acc[4][4] = {};

    for (int k0 = kbeg; k0 < kend; k0 += 64) {
        __syncthreads();
#pragma unroll
        for (int i = 0; i < 4; ++i) {
            int slot = wv * 4 + i;
            int r = slot * 8 + sr;
            int jA = sj ^ (r & 7);
            __builtin_amdgcn_global_load_lds(
                (const __attribute__((address_space(1))) void*)&A[(size_t)(row0 + r) * lda + k0 + jA * 8],
                (__attribute__((address_space(3))) void*)&As[slot * 512], 16, 0, 0);
            __builtin_amdgcn_global_load_lds(
                (const __attribute__((address_space(1))) void*)&Bw[(size_t)(col0 + r) * ldb + k0 + jA * 8],
                (__attribute__((address_space(3))) void*)&Bs[slot * 512], 16, 0, 0);
        }
        __syncthreads();
#pragma unroll
        for (int kk = 0; kk < 2; ++kk) {
            int co = kk * 32 + (lane >> 4) * 8;
            int sx = (lane & 7) << 3;
            bf16x8 af[4], bfr[4];
#pragma unroll
            for (int m = 0; m < 4; ++m) {
                int rw = wr * 64 + m * 16 + (lane & 15);
                af[m] = *reinterpret_cast<const bf16x8*>(&As[rw * 64 + (co ^ sx)]);
            }
#pragma unroll
            for (int n = 0; n < 4; ++n) {
                int rw = wc * 64 + n * 16 + (lane & 15);
                bfr[n] = *reinterpret_cast<const bf16x8*>(&Bs[rw * 64 + (co ^ sx)]);
            }
#pragma unroll
            for (int m = 0; m < 4; ++m)
#pragma unroll
                for (int n = 0; n < 4; ++n)
                    acc[m][n] = __builtin_amdgcn_mfma_f32_16x16x32_bf16(af[m], bfr[n], acc[m][n], 0, 0, 0);
        }
    }

#pragma unroll
    for (int m = 0; m < 4; ++m) {
#pragma unroll
        for (int n = 0; n < 4; ++n) {
            int col = col0 + wc * 64 + n * 16 + (lane & 15);
            if (col >= N) continue;
#pragma unroll
            for (int r = 0; r < 4; ++r) {
                int row = row0 + wr * 64 + m * 16 + (lane >> 4) * 4 + r;
                float v = acc[m][n][r];
                if (EPI == 1) {
                    v += bias[col];
                    // softplus(v) = max(v,0) + log(1+exp(-|v|)) -- fast intrinsics
                    v = fmaxf(v, 0.f) + __logf(1.f + __expf(-fabsf(v)));
                }
                if (OUTBF)
                    ((ushort_t*)C)[(size_t)row * ldc + col] = f2bf(v);
                else
                    Cf[(size_t)row * ldc + col] = v;
            }
        }
    }
}

// ---------------- split-K partial reduce (4 partials f32 -> bf16) ------------
__global__ __launch_bounds__(256) void k_red4(const float* __restrict__ p,
                                              ushort_t* __restrict__ o,
                                              int n, int stride) {
    int i = (blockIdx.x * 256 + threadIdx.x) * 4;
    if (i >= n) return;
    f32x4 a = *reinterpret_cast<const f32x4*>(&p[i]);
    f32x4 b = *reinterpret_cast<const f32x4*>(&p[i + stride]);
    f32x4 c = *reinterpret_cast<const f32x4*>(&p[i + 2 * stride]);
    f32x4 d = *reinterpret_cast<const f32x4*>(&p[i + 3 * stride]);
    ushort4 r;
    r.x = f2bf(a[0] + b[0] + c[0] + d[0]);
    r.y = f2bf(a[1] + b[1] + c[1] + d[1]);
    r.z = f2bf(a[2] + b[2] + c[2] + d[2]);
    r.w = f2bf(a[3] + b[3] + c[3] + d[3]);
    *reinterpret_cast<ushort4*>(&o[i]) = r;
}

// ---------------- depthwise causal conv (width 4) + SiLU ----------------
__global__ __launch_bounds__(256) void k_conv(const ushort_t* __restrict__ xz,
                                              const float* __restrict__ w,
                                              const float* __restrict__ bias,
                                              ushort_t* __restrict__ out) {
    int d = blockIdx.x * 256 + threadIdx.x;
    int b = blockIdx.z;
    int t0 = blockIdx.y * 128;
    float w0 = w[d * 4 + 0], w1 = w[d * 4 + 1], w2 = w[d * 4 + 2], w3 = w[d * 4 + 3];
    float bi = bias[d];
    size_t base = ((size_t)b * L_) * (2 * DI) + d;
    size_t obase = ((size_t)b * L_) * DI + d;
    float x0 = (t0 >= 3) ? bf2f(xz[base + (size_t)(t0 - 3) * (2 * DI)]) : 0.f;
    float x1 = (t0 >= 2) ? bf2f(xz[base + (size_t)(t0 - 2) * (2 * DI)]) : 0.f;
    float x2 = (t0 >= 1) ? bf2f(xz[base + (size_t)(t0 - 1) * (2 * DI)]) : 0.f;
    for (int t = t0; t < t0 + 128; ++t) {
        float cur = bf2f(xz[base + (size_t)t * (2 * DI)]);
        float v = w0 * x0 + w1 * x1 + w2 * x2 + w3 * cur + bi;
        v = v / (1.f + __expf(-v));
        out[obase + (size_t)t * DI] = f2bf(v);
        x0 = x1; x1 = x2; x2 = cur;
    }
}

// ---------------- chunked selective scan ----------------
// Phase 1: per-chunk local scan (h=0) -> chunk-final h and sum(dt)
__global__ __launch_bounds__(256) void k_scan1(
    const ushort_t* __restrict__ dt, const ushort_t* __restrict__ xm,
    const ushort_t* __restrict__ dbc, const float* __restrict__ A_log,
    float* __restrict__ hfin, float* __restrict__ dtsum) {
    __shared__ float Bsh[LC][DSTATE];
    int tid = threadIdx.x;
    int d = blockIdx.x * 256 + tid;
    int c = blockIdx.y, b = blockIdx.z;
    f32x16 arow;
    float a1 = __expf(A_log[d * DSTATE]);
    bool ok = true;
#pragma unroll
    for (int s = 0; s < DSTATE; ++s) {
        float av = __expf(A_log[d * DSTATE + s]);
        arow[s] = -av * LOG2E;
        ok = ok && (fabsf(av - (float)(s + 1) * a1) <= 1e-4f * (float)(s + 1) * fabsf(a1) + 1e-6f);
    }
    float arow0 = -a1 * LOG2E;
    size_t rbase = (size_t)b * L_ + (size_t)c * LC;
    {
        int i = tid * 4;
        int t = i >> 4, s0 = i & 15;
        u16x4 v = *reinterpret_cast<const u16x4*>(&dbc[(rbase + t) * 96 + DTR + s0]);
#pragma unroll
        for (int j = 0; j < 4; ++j) Bsh[t][s0 + j] = bf2f(v[j]);
    }
    __syncthreads();
    f32x4 h0 = {}, h1 = {}, h2 = {}, h3 = {};
    float sd = 0.f;
    if (ok) {
        for (int t = 0; t < LC; ++t) {
            size_t ro = rbase + t;
            float dtv = bf2f(dt[ro * DI + d]);
            float xv = bf2f(xm[ro * DI + d]);
            float dx = dtv * xv;
            sd += dtv;
            float p = __builtin_amdgcn_exp2f(dtv * arow0);
            float p2 = p * p, p3 = p2 * p, p4 = p2 * p2;
            f32x4 ea = {p, p2, p3, p4};
            f32x4 eb = ea * p4, ec = eb * p4, ed = ec * p4;
            const f32x4* Bq = reinterpret_cast<const f32x4*>(&Bsh[t][0]);
            h0 = h0 * ea + Bq[0] * dx;
            h1 = h1 * eb + Bq[1] * dx;
            h2 = h2 * ec + Bq[2] * dx;
            h3 = h3 * ed + Bq[3] * dx;
        }
    } else {
        for (int t = 0; t < LC; ++t) {
            size_t ro = rbase + t;
            float dtv = bf2f(dt[ro * DI + d]);
            float xv = bf2f(xm[ro * DI + d]);
            float dx = dtv * xv;
            sd += dtv;
            const f32x4* Bq = reinterpret_cast<const f32x4*>(&Bsh[t][0]);
            f32x4 e0, e1, e2, e3;
#pragma unroll
            for (int j = 0; j < 4; ++j) {
                e0[j] = __builtin_amdgcn_exp2f(dtv * arow[j]);
                e1[j] = __builtin_amdgcn_exp2f(dtv * arow[4 + j]);
                e2[j] = __builtin_amdgcn_exp2f(dtv * arow[8 + j]);
                e3[j] = __builtin_amdgcn_exp2f(dtv * arow[12 + j]);
            }
            h0 = h0 * e0 + Bq[0] * dx;
            h1 = h1 * e1 + Bq[1] * dx;
            h2 = h2 * e2 + Bq[2] * dx;
            h3 = h3 * e3 + Bq[3] * dx;
        }
    }
    size_t hbase = (((size_t)b * NC + c) * DI + d) * DSTATE;
    *reinterpret_cast<f32x4*>(&hfin[hbase + 0]) = h0;
    *reinterpret_cast<f32x4*>(&hfin[hbase + 4]) = h1;
    *reinterpret_cast<f32x4*>(&hfin[hbase + 8]) = h2;
    *reinterpret_cast<f32x4*>(&hfin[hbase + 12]) = h3;
    dtsum[((size_t)b * NC + c) * DI + d] = sd;
}

// Phase 2: sequential carry over chunks; hfin becomes carry-IN per chunk.
__global__ __launch_bounds__(256) void k_scan2(
    float* __restrict__ hfin, const float* __restrict__ dtsum,
    const float* __restrict__ A_log) {
    int gid = blockIdx.x * 256 + threadIdx.x;  // s fastest, then d, then b
    int s = gid & (DSTATE - 1);
    int d = (gid >> 4) & (DI - 1);
    int b = gid >> 15;
    float Av = -__expf(A_log[d * DSTATE + s]) * LOG2E;
    float carry = 0.f;
    for (int c = 0; c < NC; ++c) {
        size_t idx = (((size_t)b * NC + c) * DI + d) * DSTATE + s;
        float loc = hfin[idx];
        hfin[idx] = carry;
        float sd = dtsum[((size_t)b * NC + c) * DI + d];
        carry = __builtin_amdgcn_exp2f(Av * sd) * carry + loc;
    }
}

// Phase 3: local scan with carry-in + D*x + z-gating -> yg (bf16)
__global__ __launch_bounds__(256) void k_scan3(
    const ushort_t* __restrict__ dt, const ushort_t* __restrict__ xm,
    const ushort_t* __restrict__ xz, const ushort_t* __restrict__ dbc,
    const float* __restrict__ A_log, const float* __restrict__ Dp,
    const float* __restrict__ hinit, ushort_t* __restrict__ yg) {
    __shared__ float Bsh[LC][DSTATE];
    __shared__ float Csh[LC][DSTATE];
    int tid = threadIdx.x;
    int d = blockIdx.x * 256 + tid;
    int c = blockIdx.y, b = blockIdx.z;
    f32x16 arow;
    float a1 = __expf(A_log[d * DSTATE]);
    bool ok = true;
#pragma unroll
    for (int s = 0; s < DSTATE; ++s) {
        float av = __expf(A_log[d * DSTATE + s]);
        arow[s] = -av * LOG2E;
        ok = ok && (fabsf(av - (float)(s + 1) * a1) <= 1e-4f * (float)(s + 1) * fabsf(a1) + 1e-6f);
    }
    float arow0 = -a1 * LOG2E;
    float Dd = Dp[d];
    size_t rbase = (size_t)b * L_ + (size_t)c * LC;
    {
        int e0 = tid * 8;
        int t = e0 >> 5, s0 = e0 & 31;
        u16x8 v = *reinterpret_cast<const u16x8*>(&dbc[(rbase + t) * 96 + DTR + s0]);
#pragma unroll
        for (int j = 0; j < 8; ++j) {
            int s = s0 + j;
            float f = bf2f(v[j]);
            if (s < DSTATE) Bsh[t][s] = f;
            else Csh[t][s - DSTATE] = f;
        }
    }
    __syncthreads();
    size_t hbase = (((size_t)b * NC + c) * DI + d) * DSTATE;
    f32x4 h0 = *reinterpret_cast<const f32x4*>(&hinit[hbase + 0]);
    f32x4 h1 = *reinterpret_cast<const f32x4*>(&hinit[hbase + 4]);
    f32x4 h2 = *reinterpret_cast<const f32x4*>(&hinit[hbase + 8]);
    f32x4 h3 = *reinterpret_cast<const f32x4*>(&hinit[hbase + 12]);
    if (ok) {
        for (int t = 0; t < LC; ++t) {
            size_t ro = rbase + t;
            float dtv = bf2f(dt[ro * DI + d]);
            float xv = bf2f(xm[ro * DI + d]);
            float zv = bf2f(xz[ro * (2 * DI) + DI + d]);
            float dx = dtv * xv;
            float p = __builtin_amdgcn_exp2f(dtv * arow0);
            float p2 = p * p, p3 = p2 * p, p4 = p2 * p2;
            f32x4 ea = {p, p2, p3, p4};
            f32x4 eb = ea * p4, ec = eb * p4, ed = ec * p4;
            const f32x4* Bq = reinterpret_cast<const f32x4*>(&Bsh[t][0]);
            const f32x4* Cq = reinterpret_cast<const f32x4*>(&Csh[t][0]);
            h0 = h0 * ea + Bq[0] * dx;
            h1 = h1 * eb + Bq[1] * dx;
            h2 = h2 * ec + Bq[2] * dx;
            h3 = h3 * ed + Bq[3] * dx;
            f32x4 y4 = h0 * Cq[0] + h1 * Cq[1] + h2 * Cq[2] + h3 * Cq[3];
            float y = (y4[0] + y4[1]) + (y4[2] + y4[3]) + Dd * xv;
            y *= zv / (1.f + __expf(-zv));
            yg[ro * DI + d] = f2bf(y);
        }
    } else {
        for (int t = 0; t < LC; ++t) {
            size_t ro = rbase + t;
            float dtv = bf2f(dt[ro * DI + d]);
            float xv = bf2f(xm[ro * DI + d]);
            float zv = bf2f(xz[ro * (2 * DI) + DI + d]);
            float dx = dtv * xv;
            const f32x4* Bq = reinterpret_cast<const f32x4*>(&Bsh[t][0]);
            const f32x4* Cq = reinterpret_cast<const f32x4*>(&Csh[t][0]);
            f32x4 e0, e1, e2, e3;
#pragma unroll
            for (int j = 0; j < 4; ++j) {
                e0[j] = __builtin_amdgcn_exp2f(dtv * arow[j]);
                e1[j] = __builtin_amdgcn_exp2f(dtv * arow[4 + j]);
                e2[j] = __builtin_amdgcn_exp2f(dtv * arow[8 + j]);
                e3[j] = __builtin_amdgcn_exp2f(dtv * arow[12 + j]);
            }
            h0 = h0 * e0 + Bq[0] * dx;
            h1 = h1 * e1 + Bq[1] * dx;
            h2 = h2 * e2 + Bq[2] * dx;
            h3 = h3 * e3 + Bq[3] * dx;
            f32x4 y4 = h0 * Cq[0] + h1 * Cq[1] + h2 * Cq[2] + h3 * Cq[3];
            float y = (y4[0] + y4[1]) + (y4[2] + y4[3]) + Dd * xv;
            y *= zv / (1.f + __expf(-zv));
            yg[ro * DI + d] = f2bf(y);
        }
    }
}

// ---------------- residual + LayerNorm (bf16 mamba-out) ----------------
__global__ __launch_bounds__(256) void k_ln(const ushort_t* __restrict__ mo,
                                            const float* __restrict__ x,
                                            const float* __restrict__ g,
                                            const float* __restrict__ be,
                                            float* __restrict__ out) {
    __shared__ float red[8];
    size_t r = blockIdx.x;
    int tid = threadIdx.x;
    ushort4 mv = *reinterpret_cast<const ushort4*>(&mo[r * DM + tid * 4]);
    float4 xv = *reinterpret_cast<const float4*>(&x[r * DM + tid * 4]);
    float h0 = bf2f(mv.x) + xv.x, h1 = bf2f(mv.y) + xv.y;
    float h2 = bf2f(mv.z) + xv.z, h3 = bf2f(mv.w) + xv.w;
    float s = h0 + h1 + h2 + h3;
    float q = h0 * h0 + h1 * h1 + h2 * h2 + h3 * h3;
#pragma unroll
    for (int o = 32; o > 0; o >>= 1) {
        s += __shfl_down(s, o);
        q += __shfl_down(q, o);
    }
    int lane = tid & 63, wid = tid >> 6;
    if (lane == 0) { red[wid] = s; red[4 + wid] = q; }
    __syncthreads();
    s = red[0] + red[1] + red[2] + red[3];
    q = red[4] + red[5] + red[6] + red[7];
    float mu = s * (1.f / DM);
    float var = q * (1.f / DM) - mu * mu;
    float rs = rsqrtf(var + 1e-5f);
    float4 gv = *reinterpret_cast<const float4*>(&g[tid * 4]);
    float4 bv = *reinterpret_cast<const float4*>(&be[tid * 4]);
    float4 o;
    o.x = (h0 - mu) * rs * gv.x + bv.x;
    o.y = (h1 - mu) * rs * gv.y + bv.y;
    o.z = (h2 - mu) * rs * gv.z + bv.z;
    o.w = (h3 - mu) * rs * gv.w + bv.w;
    *reinterpret_cast<float4*>(&out[r * DM + tid * 4]) = o;
}

extern "C" void kernel_launch(void* const* d_in, const int* in_sizes, int n_in,
                              void* d_out, int out_size, void* d_ws, size_t ws_size,
                              hipStream_t stream) {
    const float* x      = (const float*)d_in[0];   // (B,L,DM)
    const float* w_in   = (const float*)d_in[1];   // (2*DI, DM)
    const float* conv_w = (const float*)d_in[2];   // (DI,1,4)
    const float* conv_b = (const float*)d_in[3];   // (DI)
    const float* w_xp   = (const float*)d_in[4];   // (96, DI)
    const float* w_dt   = (const float*)d_in[5];   // (DI, 64)
    const float* dt_b   = (const float*)d_in[6];   // (DI)
    const float* A_log  = (const float*)d_in[7];   // (DI,16)
    const float* Dp     = (const float*)d_in[8];   // (DI)
    const float* w_out  = (const float*)d_in[9];   // (DM, DI)
    const float* ln_g   = (const float*)d_in[10];
    const float* ln_b   = (const float*)d_in[11];
    float* out = (float*)d_out;

    char* ws = (char*)d_ws;
    size_t off = 0;
    auto alloc = [&](size_t bytes) -> void* {
        void* p = ws + off;
        off += (bytes + 255) & ~(size_t)255;
        return p;
    };
    const int M = B_ * L_;  // 8192
    ushort_t* w_in_b  = (ushort_t*)alloc((size_t)2 * DI * DM * 2);
    ushort_t* w_xp_b  = (ushort_t*)alloc((size_t)96 * DI * 2);
    ushort_t* w_dt_b  = (ushort_t*)alloc((size_t)DI * DTR * 2);
    ushort_t* w_out_b = (ushort_t*)alloc((size_t)DM * DI * 2);
    ushort_t* x_b     = (ushort_t*)alloc((size_t)M * DM * 2);   // 16.8 MB
    ushort_t* xz      = (ushort_t*)alloc((size_t)M * 2 * DI * 2);
    ushort_t* xm      = (ushort_t*)alloc((size_t)M * DI * 2);
    ushort_t* dbc     = (ushort_t*)alloc((size_t)M * 96 * 2);
    ushort_t* dtb     = (ushort_t*)alloc((size_t)M * DI * 2);   // bf16 dt (33.5 MB)
    ushort_t* yg      = (ushort_t*)alloc((size_t)M * DI * 2);
    float*    dtsum   = (float*)alloc((size_t)B_ * NC * DI * 4);
    float*    dbc_p   = (float*)alloc((size_t)4 * M * 96 * 4);  // split-K partials
    ushort_t* mo      = dtb;           // alias: dt dead after scan3 (bf16 mo fits)
    float*    hfin    = (float*)x_b;   // alias: x_b dead after in_proj

    // fused f32->bf16 conversion of all inputs (1 launch)
    k_cvt5<<<dim3(CV_E4 / 256), 256, 0, stream>>>(
        w_in, w_in_b, w_xp, w_xp_b, w_dt, w_dt_b, w_out, w_out_b, x, x_b);

    // in_proj: xz[8192,4096] = x_b @ w_in_b^T  (256x128, 3-buf, 2 blocks/CU)
    k_gemmP<1024, 4096, 32><<<dim3(1024), 512, 0, stream>>>(x_b, w_in_b, xz);
    // conv + silu
    k_conv<<<dim3(DI / 256, L_ / 128, B_), 256, 0, stream>>>(xz, conv_w, conv_b, xm);
    // x_proj (split-K=4): dbc_p[z][M,96] = xm @ w_xp[96,2048]^T (K chunk 512)
    k_gemm2<0, false><<<dim3(64, 1, 4), 256, 0, stream>>>(
        xm, w_xp_b, dbc_p, nullptr, M, 96, DI, DI, DI, 96, 64);
    k_red4<<<dim3((M * 96 / 4 + 255) / 256), 256, 0, stream>>>(dbc_p, dbc, M * 96, M * 96);
    // dt_proj + fast softplus -> bf16
    k_gemm2<1, true><<<dim3(64 * 16, 1, 1), 256, 0, stream>>>(
        dbc, w_dt_b, dtb, dt_b, M, DI, DTR, 96, DTR, DI, 64);
    // chunked selective scan
    k_scan1<<<dim3(DI / 256, NC, B_), 256, 0, stream>>>(dtb, xm, dbc, A_log, hfin, dtsum);
    k_scan2<<<dim3(B_ * DI * DSTATE / 256), 256, 0, stream>>>(hfin, dtsum, A_log);
    k_scan3<<<dim3(DI / 256, NC, B_), 256, 0, stream>>>(dtb, xm, xz, dbc, A_log, Dp, hfin, yg);
    // out_proj: mo[8192,1024](bf16) = yg @ w_out^T  (256x128, 3-buf)
    k_gemmP<2048, 1024, 64><<<dim3(256), 512, 0, stream>>>(yg, w_out_b, mo);
    // residual + layernorm
    k_ln<<<dim3(M), 256, 0, stream>>>(mo, x, ln_g, ln_b, out);
}

// Round 15
// 280.506 us; speedup vs baseline: 1.1917x; 1.0236x over previous
//
#include <hip/hip_runtime.h>
#include <hip/hip_bf16.h>

// Mamba block: B=4, L=2048, D_MODEL=1024, D_INNER=2048, D_STATE=16, DT_RANK=64
#define B_ 4
#define L_ 2048
#define DM 1024
#define DI 2048
#define DSTATE 16
#define DTR 64
#define LC 64            // scan chunk length
#define NC (L_ / LC)     // 32 chunks
#define LOG2E 1.44269504f

typedef unsigned short ushort_t;
typedef __bf16 bf16x8 __attribute__((ext_vector_type(8)));
typedef float f32x4 __attribute__((ext_vector_type(4)));
typedef float f32x16 __attribute__((ext_vector_type(16)));
typedef unsigned short u16x8 __attribute__((ext_vector_type(8)));
typedef unsigned short u16x4 __attribute__((ext_vector_type(4)));

__device__ __forceinline__ ushort_t f2bf(float f) {
    unsigned u = __builtin_bit_cast(unsigned, f);
    unsigned r = (u + 0x7FFFu + ((u >> 16) & 1u)) >> 16;
    return (ushort_t)r;
}
__device__ __forceinline__ float bf2f(ushort_t h) {
    unsigned u = ((unsigned)h) << 16;
    return __builtin_bit_cast(float, u);
}

// ---------------- fused f32 -> bf16 convert for all 5 buffers ----------------
#define CV_E0 1048576
#define CV_E1 (CV_E0 + 49152)
#define CV_E2 (CV_E1 + 32768)
#define CV_E3 (CV_E2 + 524288)
#define CV_E4 (CV_E3 + 2097152)     // total 3751936 quads = 14656 * 256
__global__ __launch_bounds__(256) void k_cvt5(
    const float* __restrict__ s0, ushort_t* __restrict__ d0,
    const float* __restrict__ s1, ushort_t* __restrict__ d1,
    const float* __restrict__ s2, ushort_t* __restrict__ d2,
    const float* __restrict__ s3, ushort_t* __restrict__ d3,
    const float* __restrict__ s4, ushort_t* __restrict__ d4) {
    int g = blockIdx.x * 256 + threadIdx.x;
    const float* s;
    ushort_t* dst;
    int i;
    if (g < CV_E0)      { s = s0; dst = d0; i = g * 4; }
    else if (g < CV_E1) { s = s1; dst = d1; i = (g - CV_E0) * 4; }
    else if (g < CV_E2) { s = s2; dst = d2; i = (g - CV_E1) * 4; }
    else if (g < CV_E3) { s = s3; dst = d3; i = (g - CV_E2) * 4; }
    else                { s = s4; dst = d4; i = (g - CV_E3) * 4; }
    float4 v = *reinterpret_cast<const float4*>(s + i);
    ushort4 o;
    o.x = f2bf(v.x); o.y = f2bf(v.y); o.z = f2bf(v.z); o.w = f2bf(v.w);
    *reinterpret_cast<ushort4*>(dst + i) = o;
}

// ============ pipelined MFMA GEMM machinery ============
#define FENCE asm volatile("" ::: "memory")
#define VM3 asm volatile("s_waitcnt vmcnt(3)" ::: "memory")
#define VM0 asm volatile("s_waitcnt vmcnt(0)" ::: "memory")

// -------- 256x128 BK=32 merged-phase GEMM, 3-buffer ring (72 KB LDS) --------
// 512 threads, 8 waves, 2 blocks/CU. Known-good (round 12).
template <int KK, int LDC, int NT>
__global__ __launch_bounds__(512, 2) void k_gemmP(const ushort_t* __restrict__ Aq,
                                                  const ushort_t* __restrict__ Bq,
                                                  ushort_t* __restrict__ C) {
    __shared__ ushort_t lds[36864];  // 72 KB: 3 buffers x (A 8192 + B 4096 elems)
    const int tid = threadIdx.x;
    const int w = tid >> 6, lane = tid & 63;
    const int l15 = lane & 15;
    const int wm = w >> 2, wn = w & 3;
    const int bid = blockIdx.x;
    const int tm = bid & 31, tn = bid >> 5;
    const int row0 = tm * 256, col0 = tn * 128;

    const int rs = w * 16 + (lane >> 2);
    const int lcs = (lane & 3) ^ ((lane >> 3) & 3);
    const int pcr = ((lane >> 4) ^ ((l15 >> 1) & 3)) * 8;
    const int aoff = wm * 4096 + l15 * 32 + pcr;
    const int boff = 8192 + wn * 1024 + l15 * 32 + pcr;

    auto stg = [&](int buf, int t) {
        const ushort_t* sa = Aq + (size_t)(row0 + rs) * KK + t * 32 + lcs * 8;
        __builtin_amdgcn_global_load_lds(
            (const __attribute__((address_space(1))) void*)sa,
            (__attribute__((address_space(3))) void*)&lds[buf * 12288 + w * 512], 16, 0, 0);
        __builtin_amdgcn_global_load_lds(
            (const __attribute__((address_space(1))) void*)(sa + (size_t)128 * KK),
            (__attribute__((address_space(3))) void*)&lds[buf * 12288 + 4096 + w * 512], 16, 0, 0);
        const ushort_t* sb = Bq + (size_t)(col0 + rs) * KK + t * 32 + lcs * 8;
        __builtin_amdgcn_global_load_lds(
            (const __attribute__((address_space(1))) void*)sb,
            (__attribute__((address_space(3))) void*)&lds[buf * 12288 + 8192 + w * 512], 16, 0, 0);
    };

    f32x4 acc[8][2] = {};

#define GPHASE(BUF, STAGE_STMT, WAIT_STMT)                                        \
    {                                                                             \
        bf16x8 av[8], bv[2];                                                      \
        _Pragma("unroll") for (int i_ = 0; i_ < 8; ++i_)                          \
            av[i_] = *(const bf16x8*)&lds[(BUF) * 12288 + aoff + i_ * 512];       \
        _Pragma("unroll") for (int i_ = 0; i_ < 2; ++i_)                          \
            bv[i_] = *(const bf16x8*)&lds[(BUF) * 12288 + boff + i_ * 512];       \
        STAGE_STMT;                                                               \
        FENCE; __builtin_amdgcn_s_barrier(); FENCE;                               \
        asm volatile("s_waitcnt lgkmcnt(0)" ::: "memory");                        \
        __builtin_amdgcn_sched_barrier(0);                                        \
        __builtin_amdgcn_s_setprio(1);                                            \
        _Pragma("unroll") for (int i_ = 0; i_ < 8; ++i_)                          \
            _Pragma("unroll") for (int j_ = 0; j_ < 2; ++j_)                      \
                acc[i_][j_] = __builtin_amdgcn_mfma_f32_16x16x32_bf16(            \
                    av[i_], bv[j_], acc[i_][j_], 0, 0, 0);                        \
        __builtin_amdgcn_s_setprio(0);                                            \
        WAIT_STMT;                                                                \
        FENCE; __builtin_amdgcn_s_barrier(); FENCE;                               \
    }

    stg(0, 0); stg(1, 1);   // 6 loads in flight
    VM3;                     // tile 0's 3 landed
    FENCE; __builtin_amdgcn_s_barrier(); FENCE;

#pragma unroll 1
    for (int k = 0; k < (NT - 2) / 3; ++k) {
        const int t0 = 3 * k;
        GPHASE(0, stg(2, t0 + 2), VM3);
        GPHASE(1, stg(0, t0 + 3), VM3);
        GPHASE(2, stg(1, t0 + 4), VM3);
    }
    if constexpr ((NT - 2) % 3 == 2) {
        GPHASE(0, stg(2, NT - 2), VM3);
        GPHASE(1, stg(0, NT - 1), VM3);
        GPHASE(2, (void)0, VM0);
        GPHASE(0, (void)0, (void)0);
    } else {
        GPHASE(0, (void)0, VM0);
        GPHASE(1, (void)0, (void)0);
    }
#undef GPHASE

#pragma unroll
    for (int mf = 0; mf < 8; ++mf)
#pragma unroll
        for (int nf = 0; nf < 2; ++nf) {
            int col = col0 + wn * 32 + nf * 16 + l15;
#pragma unroll
            for (int r = 0; r < 4; ++r) {
                int row = row0 + wm * 128 + mf * 16 + (lane >> 4) * 4 + r;
                C[(size_t)row * LDC + col] = f2bf(acc[mf][nf][r]);
            }
        }
}

// ---------------- m97-structure bf16 MFMA GEMM (x_proj / dt_proj) ------------
// EPI=1: fast branchless softplus via v_exp_f32 + v_log_f32 (round-14 win).
template <int EPI, bool OUTBF>
__global__ __launch_bounds__(256) void k_gemm2(
    const ushort_t* __restrict__ A, const ushort_t* __restrict__ Bw,
    void* __restrict__ C, const float* __restrict__ bias,
    int M, int N, int K, int lda, int ldb, int ldc, int tilesM) {
    __shared__ ushort_t As[128 * 64];
    __shared__ ushort_t Bs[128 * 64];
    int tid = threadIdx.x;
    int lane = tid & 63, wv = tid >> 6;
    int wr = wv >> 1, wc = wv & 1;
    int bid = blockIdx.x;
    int tilesN = gridDim.x / tilesM;
    int per = 8 * tilesN;
    int grp = bid / per, within = bid % per;
    int tm = grp * 8 + (within & 7);
    int tn = within >> 3;
    int row0 = tm * 128, col0 = tn * 128;
    int kchunk = K / gridDim.z;
    int kbeg = blockIdx.z * kchunk, kend = kbeg + kchunk;
    float* Cf = (float*)C + (size_t)blockIdx.z * (size_t)M * ldc;

    int sr = lane >> 3;
    int sj = lane & 7;
    f32x4 acc[4][4] = {};

    for (int k0 = kbeg; k0 < kend; k0 += 64) {
        __syncthreads();
#pragma unroll
        for (int i = 0; i < 4; ++i) {
            int slot = wv * 4 + i;
            int r = slot * 8 + sr;
            int jA = sj ^ (r & 7);
            __builtin_amdgcn_global_load_lds(
                (const __attribute__((address_space(1))) void*)&A[(size_t)(row0 + r) * lda + k0 + jA * 8],
                (__attribute__((address_space(3))) void*)&As[slot * 512], 16, 0, 0);
            __builtin_amdgcn_global_load_lds(
                (const __attribute__((address_space(1))) void*)&Bw[(size_t)(col0 + r) * ldb + k0 + jA * 8],
                (__attribute__((address_space(3))) void*)&Bs[slot * 512], 16, 0, 0);
        }
        __syncthreads();
#pragma unroll
        for (int kk = 0; kk < 2; ++kk) {
            int co = kk * 32 + (lane >> 4) * 8;
            int sx = (lane & 7) << 3;
            bf16x8 af[4], bfr[4];
#pragma unroll
            for (int m = 0; m < 4; ++m) {
                int rw = wr * 64 + m * 16 + (lane & 15);
                af[m] = *reinterpret_cast<const bf16x8*>(&As[rw * 64 + (co ^ sx)]);
            }
#pragma unroll
            for (int n = 0; n < 4; ++n) {
                int rw = wc * 64 + n * 16 + (lane & 15);
                bfr[n] = *reinterpret_cast<const bf16x8*>(&Bs[rw * 64 + (co ^ sx)]);
            }
#pragma unroll
            for (int m = 0; m < 4; ++m)
#pragma unroll
                for (int n = 0; n < 4; ++n)
                    acc[m][n] = __builtin_amdgcn_mfma_f32_16x16x32_bf16(af[m], bfr[n], acc[m][n], 0, 0, 0);
        }
    }

#pragma unroll
    for (int m = 0; m < 4; ++m) {
#pragma unroll
        for (int n = 0; n < 4; ++n) {
            int col = col0 + wc * 64 + n * 16 + (lane & 15);
            if (col >= N) continue;
#pragma unroll
            for (int r = 0; r < 4; ++r) {
                int row = row0 + wr * 64 + m * 16 + (lane >> 4) * 4 + r;
                float v = acc[m][n][r];
                if (EPI == 1) {
                    v += bias[col];
                    // softplus(v) = max(v,0) + log(1+exp(-|v|)) -- fast intrinsics
                    v = fmaxf(v, 0.f) + __logf(1.f + __expf(-fabsf(v)));
                }
                if (OUTBF)
                    ((ushort_t*)C)[(size_t)row * ldc + col] = f2bf(v);
                else
                    Cf[(size_t)row * ldc + col] = v;
            }
        }
    }
}

// ---------------- split-K partial reduce (4 partials f32 -> bf16) ------------
__global__ __launch_bounds__(256) void k_red4(const float* __restrict__ p,
                                              ushort_t* __restrict__ o,
                                              int n, int stride) {
    int i = (blockIdx.x * 256 + threadIdx.x) * 4;
    if (i >= n) return;
    f32x4 a = *reinterpret_cast<const f32x4*>(&p[i]);
    f32x4 b = *reinterpret_cast<const f32x4*>(&p[i + stride]);
    f32x4 c = *reinterpret_cast<const f32x4*>(&p[i + 2 * stride]);
    f32x4 d = *reinterpret_cast<const f32x4*>(&p[i + 3 * stride]);
    ushort4 r;
    r.x = f2bf(a[0] + b[0] + c[0] + d[0]);
    r.y = f2bf(a[1] + b[1] + c[1] + d[1]);
    r.z = f2bf(a[2] + b[2] + c[2] + d[2]);
    r.w = f2bf(a[3] + b[3] + c[3] + d[3]);
    *reinterpret_cast<ushort4*>(&o[i]) = r;
}

// ---------------- depthwise causal conv (width 4) + SiLU ----------------
// t-chunk 32 (was 128): 2048 blocks -> 32 waves/CU, 4x more loads in flight
// (latency-bound fix; +9% warm-up re-reads).
__global__ __launch_bounds__(256) void k_conv(const ushort_t* __restrict__ xz,
                                              const float* __restrict__ w,
                                              const float* __restrict__ bias,
                                              ushort_t* __restrict__ out) {
    int d = blockIdx.x * 256 + threadIdx.x;
    int b = blockIdx.z;
    int t0 = blockIdx.y * 32;
    float w0 = w[d * 4 + 0], w1 = w[d * 4 + 1], w2 = w[d * 4 + 2], w3 = w[d * 4 + 3];
    float bi = bias[d];
    size_t base = ((size_t)b * L_) * (2 * DI) + d;
    size_t obase = ((size_t)b * L_) * DI + d;
    float x0 = (t0 >= 3) ? bf2f(xz[base + (size_t)(t0 - 3) * (2 * DI)]) : 0.f;
    float x1 = (t0 >= 2) ? bf2f(xz[base + (size_t)(t0 - 2) * (2 * DI)]) : 0.f;
    float x2 = (t0 >= 1) ? bf2f(xz[base + (size_t)(t0 - 1) * (2 * DI)]) : 0.f;
    for (int t = t0; t < t0 + 32; ++t) {
        float cur = bf2f(xz[base + (size_t)t * (2 * DI)]);
        float v = w0 * x0 + w1 * x1 + w2 * x2 + w3 * cur + bi;
        v = v / (1.f + __expf(-v));
        out[obase + (size_t)t * DI] = f2bf(v);
        x0 = x1; x1 = x2; x2 = cur;
    }
}

// ---------------- chunked selective scan ----------------
// Phase 1: per-chunk local scan (h=0) -> chunk-final h and sum(dt)
__global__ __launch_bounds__(256) void k_scan1(
    const ushort_t* __restrict__ dt, const ushort_t* __restrict__ xm,
    const ushort_t* __restrict__ dbc, const float* __restrict__ A_log,
    float* __restrict__ hfin, float* __restrict__ dtsum) {
    __shared__ float Bsh[LC][DSTATE];
    int tid = threadIdx.x;
    int d = blockIdx.x * 256 + tid;
    int c = blockIdx.y, b = blockIdx.z;
    f32x16 arow;
    float a1 = __expf(A_log[d * DSTATE]);
    bool ok = true;
#pragma unroll
    for (int s = 0; s < DSTATE; ++s) {
        float av = __expf(A_log[d * DSTATE + s]);
        arow[s] = -av * LOG2E;
        ok = ok && (fabsf(av - (float)(s + 1) * a1) <= 1e-4f * (float)(s + 1) * fabsf(a1) + 1e-6f);
    }
    float arow0 = -a1 * LOG2E;
    size_t rbase = (size_t)b * L_ + (size_t)c * LC;
    {
        int i = tid * 4;
        int t = i >> 4, s0 = i & 15;
        u16x4 v = *reinterpret_cast<const u16x4*>(&dbc[(rbase + t) * 96 + DTR + s0]);
#pragma unroll
        for (int j = 0; j < 4; ++j) Bsh[t][s0 + j] = bf2f(v[j]);
    }
    __syncthreads();
    f32x4 h0 = {}, h1 = {}, h2 = {}, h3 = {};
    float sd = 0.f;
    if (ok) {
        for (int t = 0; t < LC; ++t) {
            size_t ro = rbase + t;
            float dtv = bf2f(dt[ro * DI + d]);
            float xv = bf2f(xm[ro * DI + d]);
            float dx = dtv * xv;
            sd += dtv;
            float p = __builtin_amdgcn_exp2f(dtv * arow0);
            float p2 = p * p, p3 = p2 * p, p4 = p2 * p2;
            f32x4 ea = {p, p2, p3, p4};
            f32x4 eb = ea * p4, ec = eb * p4, ed = ec * p4;
            const f32x4* Bq = reinterpret_cast<const f32x4*>(&Bsh[t][0]);
            h0 = h0 * ea + Bq[0] * dx;
            h1 = h1 * eb + Bq[1] * dx;
            h2 = h2 * ec + Bq[2] * dx;
            h3 = h3 * ed + Bq[3] * dx;
        }
    } else {
        for (int t = 0; t < LC; ++t) {
            size_t ro = rbase + t;
            float dtv = bf2f(dt[ro * DI + d]);
            float xv = bf2f(xm[ro * DI + d]);
            float dx = dtv * xv;
            sd += dtv;
            const f32x4* Bq = reinterpret_cast<const f32x4*>(&Bsh[t][0]);
            f32x4 e0, e1, e2, e3;
#pragma unroll
            for (int j = 0; j < 4; ++j) {
                e0[j] = __builtin_amdgcn_exp2f(dtv * arow[j]);
                e1[j] = __builtin_amdgcn_exp2f(dtv * arow[4 + j]);
                e2[j] = __builtin_amdgcn_exp2f(dtv * arow[8 + j]);
                e3[j] = __builtin_amdgcn_exp2f(dtv * arow[12 + j]);
            }
            h0 = h0 * e0 + Bq[0] * dx;
            h1 = h1 * e1 + Bq[1] * dx;
            h2 = h2 * e2 + Bq[2] * dx;
            h3 = h3 * e3 + Bq[3] * dx;
        }
    }
    size_t hbase = (((size_t)b * NC + c) * DI + d) * DSTATE;
    *reinterpret_cast<f32x4*>(&hfin[hbase + 0]) = h0;
    *reinterpret_cast<f32x4*>(&hfin[hbase + 4]) = h1;
    *reinterpret_cast<f32x4*>(&hfin[hbase + 8]) = h2;
    *reinterpret_cast<f32x4*>(&hfin[hbase + 12]) = h3;
    dtsum[((size_t)b * NC + c) * DI + d] = sd;
}

// Phase 2: sequential carry over chunks; hfin becomes carry-IN per chunk.
__global__ __launch_bounds__(256) void k_scan2(
    float* __restrict__ hfin, const float* __restrict__ dtsum,
    const float* __restrict__ A_log) {
    int gid = blockIdx.x * 256 + threadIdx.x;  // s fastest, then d, then b
    int s = gid & (DSTATE - 1);
    int d = (gid >> 4) & (DI - 1);
    int b = gid >> 15;
    float Av = -__expf(A_log[d * DSTATE + s]) * LOG2E;
    float carry = 0.f;
    for (int c = 0; c < NC; ++c) {
        size_t idx = (((size_t)b * NC + c) * DI + d) * DSTATE + s;
        float loc = hfin[idx];
        hfin[idx] = carry;
        float sd = dtsum[((size_t)b * NC + c) * DI + d];
        carry = __builtin_amdgcn_exp2f(Av * sd) * carry + loc;
    }
}

// Phase 3: local scan with carry-in + D*x + z-gating -> yg (bf16)
__global__ __launch_bounds__(256) void k_scan3(
    const ushort_t* __restrict__ dt, const ushort_t* __restrict__ xm,
    const ushort_t* __restrict__ xz, const ushort_t* __restrict__ dbc,
    const float* __restrict__ A_log, const float* __restrict__ Dp,
    const float* __restrict__ hinit, ushort_t* __restrict__ yg) {
    __shared__ float Bsh[LC][DSTATE];
    __shared__ float Csh[LC][DSTATE];
    int tid = threadIdx.x;
    int d = blockIdx.x * 256 + tid;
    int c = blockIdx.y, b = blockIdx.z;
    f32x16 arow;
    float a1 = __expf(A_log[d * DSTATE]);
    bool ok = true;
#pragma unroll
    for (int s = 0; s < DSTATE; ++s) {
        float av = __expf(A_log[d * DSTATE + s]);
        arow[s] = -av * LOG2E;
        ok = ok && (fabsf(av - (float)(s + 1) * a1) <= 1e-4f * (float)(s + 1) * fabsf(a1) + 1e-6f);
    }
    float arow0 = -a1 * LOG2E;
    float Dd = Dp[d];
    size_t rbase = (size_t)b * L_ + (size_t)c * LC;
    {
        int e0 = tid * 8;
        int t = e0 >> 5, s0 = e0 & 31;
        u16x8 v = *reinterpret_cast<const u16x8*>(&dbc[(rbase + t) * 96 + DTR + s0]);
#pragma unroll
        for (int j = 0; j < 8; ++j) {
            int s = s0 + j;
            float f = bf2f(v[j]);
            if (s < DSTATE) Bsh[t][s] = f;
            else Csh[t][s - DSTATE] = f;
        }
    }
    __syncthreads();
    size_t hbase = (((size_t)b * NC + c) * DI + d) * DSTATE;
    f32x4 h0 = *reinterpret_cast<const f32x4*>(&hinit[hbase + 0]);
    f32x4 h1 = *reinterpret_cast<const f32x4*>(&hinit[hbase + 4]);
    f32x4 h2 = *reinterpret_cast<const f32x4*>(&hinit[hbase + 8]);
    f32x4 h3 = *reinterpret_cast<const f32x4*>(&hinit[hbase + 12]);
    if (ok) {
        for (int t = 0; t < LC; ++t) {
            size_t ro = rbase + t;
            float dtv = bf2f(dt[ro * DI + d]);
            float xv = bf2f(xm[ro * DI + d]);
            float zv = bf2f(xz[ro * (2 * DI) + DI + d]);
            float dx = dtv * xv;
            float p = __builtin_amdgcn_exp2f(dtv * arow0);
            float p2 = p * p, p3 = p2 * p, p4 = p2 * p2;
            f32x4 ea = {p, p2, p3, p4};
            f32x4 eb = ea * p4, ec = eb * p4, ed = ec * p4;
            const f32x4* Bq = reinterpret_cast<const f32x4*>(&Bsh[t][0]);
            const f32x4* Cq = reinterpret_cast<const f32x4*>(&Csh[t][0]);
            h0 = h0 * ea + Bq[0] * dx;
            h1 = h1 * eb + Bq[1] * dx;
            h2 = h2 * ec + Bq[2] * dx;
            h3 = h3 * ed + Bq[3] * dx;
            f32x4 y4 = h0 * Cq[0] + h1 * Cq[1] + h2 * Cq[2] + h3 * Cq[3];
            float y = (y4[0] + y4[1]) + (y4[2] + y4[3]) + Dd * xv;
            y *= zv / (1.f + __expf(-zv));
            yg[ro * DI + d] = f2bf(y);
        }
    } else {
        for (int t = 0; t < LC; ++t) {
            size_t ro = rbase + t;
            float dtv = bf2f(dt[ro * DI + d]);
            float xv = bf2f(xm[ro * DI + d]);
            float zv = bf2f(xz[ro * (2 * DI) + DI + d]);
            float dx = dtv * xv;
            const f32x4* Bq = reinterpret_cast<const f32x4*>(&Bsh[t][0]);
            const f32x4* Cq = reinterpret_cast<const f32x4*>(&Csh[t][0]);
            f32x4 e0, e1, e2, e3;
#pragma unroll
            for (int j = 0; j < 4; ++j) {
                e0[j] = __builtin_amdgcn_exp2f(dtv * arow[j]);
                e1[j] = __builtin_amdgcn_exp2f(dtv * arow[4 + j]);
                e2[j] = __builtin_amdgcn_exp2f(dtv * arow[8 + j]);
                e3[j] = __builtin_amdgcn_exp2f(dtv * arow[12 + j]);
            }
            h0 = h0 * e0 + Bq[0] * dx;
            h1 = h1 * e1 + Bq[1] * dx;
            h2 = h2 * e2 + Bq[2] * dx;
            h3 = h3 * e3 + Bq[3] * dx;
            f32x4 y4 = h0 * Cq[0] + h1 * Cq[1] + h2 * Cq[2] + h3 * Cq[3];
            float y = (y4[0] + y4[1]) + (y4[2] + y4[3]) + Dd * xv;
            y *= zv / (1.f + __expf(-zv));
            yg[ro * DI + d] = f2bf(y);
        }
    }
}

// ---------------- residual + LayerNorm (bf16 mamba-out) ----------------
__global__ __launch_bounds__(256) void k_ln(const ushort_t* __restrict__ mo,
                                            const float* __restrict__ x,
                                            const float* __restrict__ g,
                                            const float* __restrict__ be,
                                            float* __restrict__ out) {
    __shared__ float red[8];
    size_t r = blockIdx.x;
    int tid = threadIdx.x;
    ushort4 mv = *reinterpret_cast<const ushort4*>(&mo[r * DM + tid * 4]);
    float4 xv = *reinterpret_cast<const float4*>(&x[r * DM + tid * 4]);
    float h0 = bf2f(mv.x) + xv.x, h1 = bf2f(mv.y) + xv.y;
    float h2 = bf2f(mv.z) + xv.z, h3 = bf2f(mv.w) + xv.w;
    float s = h0 + h1 + h2 + h3;
    float q = h0 * h0 + h1 * h1 + h2 * h2 + h3 * h3;
#pragma unroll
    for (int o = 32; o > 0; o >>= 1) {
        s += __shfl_down(s, o);
        q += __shfl_down(q, o);
    }
    int lane = tid & 63, wid = tid >> 6;
    if (lane == 0) { red[wid] = s; red[4 + wid] = q; }
    __syncthreads();
    s = red[0] + red[1] + red[2] + red[3];
    q = red[4] + red[5] + red[6] + red[7];
    float mu = s * (1.f / DM);
    float var = q * (1.f / DM) - mu * mu;
    float rs = rsqrtf(var + 1e-5f);
    float4 gv = *reinterpret_cast<const float4*>(&g[tid * 4]);
    float4 bv = *reinterpret_cast<const float4*>(&be[tid * 4]);
    float4 o;
    o.x = (h0 - mu) * rs * gv.x + bv.x;
    o.y = (h1 - mu) * rs * gv.y + bv.y;
    o.z = (h2 - mu) * rs * gv.z + bv.z;
    o.w = (h3 - mu) * rs * gv.w + bv.w;
    *reinterpret_cast<float4*>(&out[r * DM + tid * 4]) = o;
}

extern "C" void kernel_launch(void* const* d_in, const int* in_sizes, int n_in,
                              void* d_out, int out_size, void* d_ws, size_t ws_size,
                              hipStream_t stream) {
    const float* x      = (const float*)d_in[0];   // (B,L,DM)
    const float* w_in   = (const float*)d_in[1];   // (2*DI, DM)
    const float* conv_w = (const float*)d_in[2];   // (DI,1,4)
    const float* conv_b = (const float*)d_in[3];   // (DI)
    const float* w_xp   = (const float*)d_in[4];   // (96, DI)
    const float* w_dt   = (const float*)d_in[5];   // (DI, 64)
    const float* dt_b   = (const float*)d_in[6];   // (DI)
    const float* A_log  = (const float*)d_in[7];   // (DI,16)
    const float* Dp     = (const float*)d_in[8];   // (DI)
    const float* w_out  = (const float*)d_in[9];   // (DM, DI)
    const float* ln_g   = (const float*)d_in[10];
    const float* ln_b   = (const float*)d_in[11];
    float* out = (float*)d_out;

    char* ws = (char*)d_ws;
    size_t off = 0;
    auto alloc = [&](size_t bytes) -> void* {
        void* p = ws + off;
        off += (bytes + 255) & ~(size_t)255;
        return p;
    };
    const int M = B_ * L_;  // 8192
    ushort_t* w_in_b  = (ushort_t*)alloc((size_t)2 * DI * DM * 2);
    ushort_t* w_xp_b  = (ushort_t*)alloc((size_t)96 * DI * 2);
    ushort_t* w_dt_b  = (ushort_t*)alloc((size_t)DI * DTR * 2);
    ushort_t* w_out_b = (ushort_t*)alloc((size_t)DM * DI * 2);
    ushort_t* x_b     = (ushort_t*)alloc((size_t)M * DM * 2);   // 16.8 MB
    ushort_t* xz      = (ushort_t*)alloc((size_t)M * 2 * DI * 2);
    ushort_t* xm      = (ushort_t*)alloc((size_t)M * DI * 2);
    ushort_t* dbc     = (ushort_t*)alloc((size_t)M * 96 * 2);
    ushort_t* dtb     = (ushort_t*)alloc((size_t)M * DI * 2);   // bf16 dt (33.5 MB)
    ushort_t* yg      = (ushort_t*)alloc((size_t)M * DI * 2);
    float*    dtsum   = (float*)alloc((size_t)B_ * NC * DI * 4);
    float*    dbc_p   = (float*)alloc((size_t)4 * M * 96 * 4);  // split-K partials
    ushort_t* mo      = dtb;           // alias: dt dead after scan3 (bf16 mo fits)
    float*    hfin    = (float*)x_b;   // alias: x_b dead after in_proj

    // fused f32->bf16 conversion of all inputs (1 launch)
    k_cvt5<<<dim3(CV_E4 / 256), 256, 0, stream>>>(
        w_in, w_in_b, w_xp, w_xp_b, w_dt, w_dt_b, w_out, w_out_b, x, x_b);

    // in_proj: xz[8192,4096] = x_b @ w_in_b^T  -- two N-half launches
    // (neutral perf, drops the profiling cut so tier-2 kernels are visible)
    k_gemmP<1024, 4096, 32><<<dim3(512), 512, 0, stream>>>(x_b, w_in_b, xz);
    k_gemmP<1024, 4096, 32><<<dim3(512), 512, 0, stream>>>(
        x_b, w_in_b + (size_t)2048 * 1024, xz + 2048);
    // conv + silu (t-chunk 32 -> 32 waves/CU)
    k_conv<<<dim3(DI / 256, L_ / 32, B_), 256, 0, stream>>>(xz, conv_w, conv_b, xm);
    // x_proj (split-K=4): dbc_p[z][M,96] = xm @ w_xp[96,2048]^T (K chunk 512)
    k_gemm2<0, false><<<dim3(64, 1, 4), 256, 0, stream>>>(
        xm, w_xp_b, dbc_p, nullptr, M, 96, DI, DI, DI, 96, 64);
    k_red4<<<dim3((M * 96 / 4 + 255) / 256), 256, 0, stream>>>(dbc_p, dbc, M * 96, M * 96);
    // dt_proj + fast softplus -> bf16
    k_gemm2<1, true><<<dim3(64 * 16, 1, 1), 256, 0, stream>>>(
        dbc, w_dt_b, dtb, dt_b, M, DI, DTR, 96, DTR, DI, 64);
    // chunked selective scan
    k_scan1<<<dim3(DI / 256, NC, B_), 256, 0, stream>>>(dtb, xm, dbc, A_log, hfin, dtsum);
    k_scan2<<<dim3(B_ * DI * DSTATE / 256), 256, 0, stream>>>(hfin, dtsum, A_log);
    k_scan3<<<dim3(DI / 256, NC, B_), 256, 0, stream>>>(dtb, xm, xz, dbc, A_log, Dp, hfin, yg);
    // out_proj: mo[8192,1024](bf16) = yg @ w_out^T  (256x128, 3-buf)
    k_gemmP<2048, 1024, 64><<<dim3(256), 512, 0, stream>>>(yg, w_out_b, mo);
    // residual + layernorm
    k_ln<<<dim3(M), 256, 0, stream>>>(mo, x, ln_g, ln_b, out);
}